// Round 5
// baseline (1371.889 us; speedup 1.0000x reference)
//
#include <hip/hip_runtime.h>

#define DIMX 3072
#define STX 512
#define SIX 1024
#define SQX 1536
#define FFX 12288

typedef __attribute__((ext_vector_type(4))) float f32x4;
typedef __attribute__((ext_vector_type(8))) __bf16 bf16x8;
typedef __attribute__((ext_vector_type(4))) int i32x4;

__device__ __forceinline__ unsigned short f2bf(float f){
  unsigned u = __builtin_bit_cast(unsigned, f);
  u += 0x7FFFu + ((u>>16)&1u);
  return (unsigned short)(u>>16);
}
__device__ __forceinline__ float bf2f(unsigned short h){
  unsigned u = ((unsigned)h)<<16;
  return __builtin_bit_cast(float, u);
}
__device__ __forceinline__ float gelu_tanh(float x){
  float x3 = x*x*x;
  float z = 0.7978845608028654f*(x + 0.044715f*x3);
  z = fminf(fmaxf(z, -15.f), 15.f);
  float e = exp2f(z*2.8853900817779268f);   // e^(2z)
  float th = (e-1.f)/(e+1.f);
  return 0.5f*x*(1.f+th);
}

// async global->LDS, 16B per lane; lds base must be wave-uniform
__device__ __forceinline__ void gload16(const void* g, void* l){
  __builtin_amdgcn_global_load_lds(
      (const __attribute__((address_space(1))) void*)g,
      (__attribute__((address_space(3))) void*)l,
      16, 0, 0);
}

// ---------------- small kernels ----------------

__global__ void k_silu(const float* __restrict__ temb, float* __restrict__ out){
  int i = blockIdx.x*256 + threadIdx.x;
  if(i < DIMX){
    float x = temb[i];
    out[i] = x / (1.f + exp2f(-x*1.4426950408889634f));
  }
}

// mod layout: mod[mat][j][i], mat in {0=img,1=txt}, j in 0..5, i in 0..3071
__global__ void k_modinit(const float* __restrict__ b_img, const float* __restrict__ b_txt,
                          float* __restrict__ mod){
  int idx = blockIdx.x*256 + threadIdx.x;   // 0..36863
  int mat = idx / 18432; int r = idx % 18432;
  int i = r/6, j = r%6;
  const float* b = mat ? b_txt : b_img;
  mod[mat*18432 + j*3072 + i] = b[r];
}

// grid: 2 mats * 18 col-chunks * 8 k-chunks = 288 blocks of 256
__global__ void k_modgemv(const float* __restrict__ w_img, const float* __restrict__ w_txt,
                          const float* __restrict__ silu_t, float* __restrict__ mod){
  int bz = blockIdx.x;
  int ks = bz & 7; bz >>= 3;
  int nc = bz % 18; int mat = bz / 18;
  const float* W = mat ? w_txt : w_img;
  __shared__ float st[384];
  int k0 = ks*384;
  for(int i = threadIdx.x; i < 384; i += 256) st[i] = silu_t[k0+i];
  __syncthreads();
  int n0 = nc*1024 + threadIdx.x*4;
  float ax=0.f, ay=0.f, az=0.f, aw=0.f;
  const float* Wp = W + (size_t)k0*18432 + n0;
  #pragma unroll 4
  for(int k=0;k<384;k++){
    float4 w = *(const float4*)(Wp + (size_t)k*18432);
    float s = st[k];
    ax += s*w.x; ay += s*w.y; az += s*w.z; aw += s*w.w;
  }
  float* md = mod + mat*18432;
  float vals[4] = {ax, ay, az, aw};
  #pragma unroll
  for(int j=0;j<4;j++){
    int n = n0+j; int i = n/6, jj = n%6;
    atomicAdd(&md[jj*3072 + i], vals[j]);
  }
}

// out[row][col] = res[row][col] + gate[col]*bias[col]; M rows x 3072 cols
__global__ void k_initC(float* __restrict__ out, const float* __restrict__ res,
                        const float* __restrict__ gate, const float* __restrict__ bias){
  int i = (blockIdx.x*256 + threadIdx.x)*4;
  int col = i % 3072;
  float4 r = *(const float4*)(res + i);
  float4 g = *(const float4*)(gate + col);
  float4 b = *(const float4*)(bias + col);
  float4 o = {r.x + g.x*b.x, r.y + g.y*b.y, r.z + g.z*b.z, r.w + g.w*b.w};
  *(float4*)(out + i) = o;
}

// f32 -> bf16 stream convert (n4 float4 groups)
__global__ void k_f2b(const float* __restrict__ x, unsigned short* __restrict__ y, int n4){
  int i = blockIdx.x*256 + threadIdx.x;
  if(i < n4){
    float4 v = *(const float4*)(x + (size_t)i*4);
    unsigned short h0 = f2bf(v.x), h1 = f2bf(v.y), h2 = f2bf(v.z), h3 = f2bf(v.w);
    unsigned long long pk = (unsigned long long)(h0 | ((unsigned)h1<<16))
                          | ((unsigned long long)(h2 | ((unsigned)h3<<16))<<32);
    *(unsigned long long*)(y + (size_t)i*4) = pk;
  }
}

// LayerNorm (no affine) + modulate: out_bf16 = (x-mu)*rstd*(scale+1) + shift
__global__ void k_lnmod(const float* __restrict__ x, const float* __restrict__ modp,
                        unsigned short* __restrict__ out){
  int row = blockIdx.x, t = threadIdx.x;
  const float* xr = x + (size_t)row*DIMX;
  float4 v0 = *(const float4*)(xr + t*4);
  float4 v1 = *(const float4*)(xr + 1024 + t*4);
  float4 v2 = *(const float4*)(xr + 2048 + t*4);
  float s  = v0.x+v0.y+v0.z+v0.w + v1.x+v1.y+v1.z+v1.w + v2.x+v2.y+v2.z+v2.w;
  float s2 = v0.x*v0.x+v0.y*v0.y+v0.z*v0.z+v0.w*v0.w
           + v1.x*v1.x+v1.y*v1.y+v1.z*v1.z+v1.w*v1.w
           + v2.x*v2.x+v2.y*v2.y+v2.z*v2.z+v2.w*v2.w;
  #pragma unroll
  for(int o=32;o>0;o>>=1){ s += __shfl_xor(s,o); s2 += __shfl_xor(s2,o); }
  __shared__ float rs_[4], rs2_[4];
  int wid = t>>6;
  if((t&63)==0){ rs_[wid]=s; rs2_[wid]=s2; }
  __syncthreads();
  float S  = rs_[0]+rs_[1]+rs_[2]+rs_[3];
  float S2 = rs2_[0]+rs2_[1]+rs2_[2]+rs2_[3];
  float mu = S*(1.f/3072.f);
  float var = S2*(1.f/3072.f) - mu*mu;
  float rstd = rsqrtf(var + 1e-6f);
  #pragma unroll
  for(int j=0;j<3;j++){
    int c = j*1024 + t*4;
    float4 sh = *(const float4*)(modp + c);
    float4 sc = *(const float4*)(modp + 3072 + c);
    float4 xv = (j==0)?v0:((j==1)?v1:v2);
    unsigned short h0 = f2bf((xv.x-mu)*rstd*(sc.x+1.f)+sh.x);
    unsigned short h1 = f2bf((xv.y-mu)*rstd*(sc.y+1.f)+sh.y);
    unsigned short h2 = f2bf((xv.z-mu)*rstd*(sc.z+1.f)+sh.z);
    unsigned short h3 = f2bf((xv.w-mu)*rstd*(sc.w+1.f)+sh.w);
    unsigned long long pk = (unsigned long long)(h0 | ((unsigned)h1<<16))
                          | ((unsigned long long)(h2 | ((unsigned)h3<<16))<<32);
    *(unsigned long long*)(out + (size_t)row*DIMX + c) = pk;
  }
}

// RMSNorm(q,k) + RoPE, V passthrough. grid (1536, 24), block 64.
__global__ void k_rmsrope(const unsigned short* __restrict__ qkv_txt,
                          const unsigned short* __restrict__ qkv_img,
                          const float* __restrict__ nqw, const float* __restrict__ nkw,
                          const float* __restrict__ naqw, const float* __restrict__ nakw,
                          const float* __restrict__ cosb, const float* __restrict__ sinb,
                          unsigned short* __restrict__ Q, unsigned short* __restrict__ K,
                          unsigned short* __restrict__ V){
  int s = blockIdx.x, h = blockIdx.y, t = threadIdx.x;
  bool txt = s < STX;
  const unsigned short* src = txt ? (qkv_txt + (size_t)s*9216)
                                  : (qkv_img + (size_t)(s-STX)*9216);
  const float* qw = txt ? naqw : nqw;
  const float* kw = txt ? nakw : nkw;
  int d0 = 2*t;
  float q1 = bf2f(src[h*128 + d0]),        q2 = bf2f(src[h*128 + d0 + 1]);
  float k1 = bf2f(src[3072 + h*128 + d0]), k2 = bf2f(src[3072 + h*128 + d0 + 1]);
  float v1 = bf2f(src[6144 + h*128 + d0]), v2 = bf2f(src[6144 + h*128 + d0 + 1]);
  float sq = q1*q1 + q2*q2, sk = k1*k1 + k2*k2;
  #pragma unroll
  for(int o=32;o>0;o>>=1){ sq += __shfl_xor(sq,o); sk += __shfl_xor(sk,o); }
  float rq = rsqrtf(sq*(1.f/128.f) + 1e-6f);
  float rk = rsqrtf(sk*(1.f/128.f) + 1e-6f);
  q1 *= rq*qw[d0]; q2 *= rq*qw[d0+1];
  k1 *= rk*kw[d0]; k2 *= rk*kw[d0+1];
  float c1 = cosb[(size_t)s*128 + d0], c2 = cosb[(size_t)s*128 + d0 + 1];
  float s1 = sinb[(size_t)s*128 + d0], s2 = sinb[(size_t)s*128 + d0 + 1];
  float Q1 = q1*c1 - q2*s1, Q2 = q2*c2 + q1*s2;
  float K1 = k1*c1 - k2*s1, K2 = k2*c2 + k1*s2;
  size_t o = ((size_t)s*24 + h)*128 + d0;
  Q[o] = f2bf(Q1); Q[o+1] = f2bf(Q2);
  K[o] = f2bf(K1); K[o+1] = f2bf(K2);
  V[o] = f2bf(v1); V[o+1] = f2bf(v2);
}

// V[s][h][d] -> VT[h][d][s]. grid (24 s-tiles, 24 heads), block 256.
__global__ void k_vtrans(const unsigned short* __restrict__ V, unsigned short* __restrict__ VT){
  __shared__ unsigned short tile[64][136];
  int st = blockIdx.x, h = blockIdx.y, t = threadIdx.x;
  int s0 = st*64;
  {
    int s = t>>2;
    #pragma unroll
    for(int i=0;i<4;i++){
      int oct = ((t&3)<<2) + i;     // 0..15
      i32x4 d = *(const i32x4*)(V + ((size_t)(s0+s)*24 + h)*128 + oct*8);
      *(i32x4*)&tile[s][oct*8] = d;
    }
  }
  __syncthreads();
  {
    int d0 = t>>3; int strip = t&7;
    #pragma unroll
    for(int i=0;i<4;i++){
      int d = d0 + i*32;
      unsigned short h8[8];
      #pragma unroll
      for(int j=0;j<8;j++) h8[j] = tile[strip*8 + j][d];
      unsigned a0 = h8[0] | ((unsigned)h8[1]<<16);
      unsigned a1 = h8[2] | ((unsigned)h8[3]<<16);
      unsigned a2 = h8[4] | ((unsigned)h8[5]<<16);
      unsigned a3 = h8[6] | ((unsigned)h8[7]<<16);
      i32x4 dv = {(int)a0,(int)a1,(int)a2,(int)a3};
      *(i32x4*)(VT + ((size_t)h*128 + d)*1536 + s0 + strip*8) = dv;
    }
  }
}

// row softmax in place on bf16 rows of length 1536. grid = #rows, block 256.
__global__ void k_softmax(unsigned short* __restrict__ S){
  size_t row = blockIdx.x;
  unsigned short* p = S + row*1536;
  int t = threadIdx.x;
  float v[6];
  float m = -1e30f;
  #pragma unroll
  for(int j=0;j<6;j++){ v[j] = bf2f(p[t + j*256]); m = fmaxf(m, v[j]); }
  #pragma unroll
  for(int o=32;o>0;o>>=1) m = fmaxf(m, __shfl_xor(m, o));
  __shared__ float red[4];
  int wid = t>>6;
  if((t&63)==0) red[wid] = m;
  __syncthreads();
  float M = fmaxf(fmaxf(red[0],red[1]), fmaxf(red[2],red[3]));
  __syncthreads();
  float s = 0.f;
  #pragma unroll
  for(int j=0;j<6;j++){ v[j] = exp2f((v[j]-M)*1.4426950408889634f); s += v[j]; }
  #pragma unroll
  for(int o=32;o>0;o>>=1) s += __shfl_xor(s, o);
  if((t&63)==0) red[wid] = s;
  __syncthreads();
  float inv = 1.f/(red[0]+red[1]+red[2]+red[3]);
  #pragma unroll
  for(int j=0;j<6;j++) p[t + j*256] = f2bf(v[j]*inv);
}

// ---------------- MFMA GEMM, bf16 A, bf16 B^T (activations) ----------------
// C[M,N] = epilogue(alpha * A[M,K] @ BT[N,K]^T + bias)
// mode 0: bf16 out (+bias)   mode 1: gelu(v+bias) -> bf16
// mode 3: atomicAdd(C_f32, (gate?gate[col]:1) * alpha*acc)
// split-K: blockIdx.z = zh*KS + zs
__global__ __launch_bounds__(256,4) void k_gemm(
    const unsigned short* __restrict__ A, long lda, long sAz,
    const unsigned short* __restrict__ BT, long ldb, long sBz,
    const float* __restrict__ bias,
    void* __restrict__ Cp, long ldc, long sCz,
    int K, int KS, int mode, float alpha,
    const float* __restrict__ gate)
{
  __shared__ unsigned short Als[128*32];
  __shared__ unsigned short Bls[128*32];
  const int t = threadIdx.x;
  const int bn = blockIdx.x, bm = blockIdx.y;
  const int z = blockIdx.z, zh = z / KS, zs = z - zh*KS;
  const int Kc = K / KS, kbeg = zs*Kc, kend = kbeg + Kc;

  const unsigned short* Ab = A  + (size_t)zh*sAz + (size_t)bm*128*lda;
  const unsigned short* Bb = BT + (size_t)zh*sBz + (size_t)bn*128*ldb;

  const int lane = t & 63, wid = t>>6, wr = wid>>1, wc = wid&1;
  const int lr = lane & 15, lk = lane>>4;
  const int srow = (lane>>2);
  const int soff = (lane&3)*8;

  f32x4 acc[4][4];
  #pragma unroll
  for(int i=0;i<4;i++)
    #pragma unroll
    for(int j=0;j<4;j++) acc[i][j] = {0.f,0.f,0.f,0.f};

  for(int k0=kbeg; k0<kend; k0+=32){
    __syncthreads();
    gload16(Ab + (size_t)(     wid*16 + srow)*lda + k0 + soff, Als + (     wid*16)*32);
    gload16(Ab + (size_t)(64 + wid*16 + srow)*lda + k0 + soff, Als + (64 + wid*16)*32);
    gload16(Bb + (size_t)(     wid*16 + srow)*ldb + k0 + soff, Bls + (     wid*16)*32);
    gload16(Bb + (size_t)(64 + wid*16 + srow)*ldb + k0 + soff, Bls + (64 + wid*16)*32);
    __syncthreads();
    bf16x8 af[4], bfr[4];
    #pragma unroll
    for(int mf=0;mf<4;mf++) af[mf]  = *(const bf16x8*)&Als[(wr*64 + mf*16 + lr)*32 + lk*8];
    #pragma unroll
    for(int nf=0;nf<4;nf++) bfr[nf] = *(const bf16x8*)&Bls[(wc*64 + nf*16 + lr)*32 + lk*8];
    #pragma unroll
    for(int mf=0;mf<4;mf++)
      #pragma unroll
      for(int nf=0;nf<4;nf++)
        acc[mf][nf] = __builtin_amdgcn_mfma_f32_16x16x32_bf16(af[mf], bfr[nf], acc[mf][nf], 0,0,0);
  }

  unsigned short* C16 = (unsigned short*)Cp + (size_t)zh*sCz;
  float* C32 = (float*)Cp + (size_t)zh*sCz;
  #pragma unroll
  for(int mf=0;mf<4;mf++){
    #pragma unroll
    for(int nf=0;nf<4;nf++){
      #pragma unroll
      for(int r=0;r<4;r++){
        size_t row = (size_t)bm*128 + wr*64 + mf*16 + lk*4 + r;
        size_t col = (size_t)bn*128 + wc*64 + nf*16 + lr;
        float v = acc[mf][nf][r]*alpha;
        if(mode==0){
          C16[row*ldc + col] = f2bf(v + (bias ? bias[col] : 0.f));
        } else if(mode==1){
          C16[row*ldc + col] = f2bf(gelu_tanh(v + (bias ? bias[col] : 0.f)));
        } else {
          float g = gate ? gate[col] : 1.f;
          atomicAdd(&C32[row*ldc + col], g*v);
        }
      }
    }
  }
}

// ---------------- MFMA GEMM, bf16 A, fp32 W[K][N] (weights, JIT convert) ----
// C[M,N] = epilogue(A[M,K] @ W[K][N] + bias); same modes as k_gemm.
__global__ __launch_bounds__(256,4) void k_gemmW(
    const unsigned short* __restrict__ A, long lda,
    const float* __restrict__ W, long ldw,
    const float* __restrict__ bias,
    void* __restrict__ Cp, long ldc,
    int K, int KS, int mode,
    const float* __restrict__ gate)
{
  __shared__ unsigned short Als[128*32];
  __shared__ float BlsW[32*128];
  const int t = threadIdx.x;
  const int bn = blockIdx.x, bm = blockIdx.y;
  const int zs = blockIdx.z;
  const int Kc = K / KS, kbeg = zs*Kc, kend = kbeg + Kc;

  const unsigned short* Ab = A + (size_t)bm*128*lda;
  const float* Wb = W + (size_t)bn*128;

  const int lane = t & 63, wid = t>>6, wr = wid>>1, wc = wid&1;
  const int lr = lane & 15, lk = lane>>4;
  const int srow = (lane>>2);
  const int soff = (lane&3)*8;
  const int wrow = (lane>>5);        // B staging: row within pair
  const int wcol = (lane&31)*4;      // B staging: 4-float chunk

  f32x4 acc[4][4];
  #pragma unroll
  for(int i=0;i<4;i++)
    #pragma unroll
    for(int j=0;j<4;j++) acc[i][j] = {0.f,0.f,0.f,0.f};

  for(int k0=kbeg; k0<kend; k0+=32){
    __syncthreads();
    // A: 128 rows x 32 bf16
    gload16(Ab + (size_t)(     wid*16 + srow)*lda + k0 + soff, Als + (     wid*16)*32);
    gload16(Ab + (size_t)(64 + wid*16 + srow)*lda + k0 + soff, Als + (64 + wid*16)*32);
    // W: 32 k-rows x 128 f32; wave issue i covers rows [wid*8 + i*2, +2)
    #pragma unroll
    for(int i=0;i<4;i++){
      int r0 = wid*8 + i*2;
      gload16(Wb + (size_t)(k0 + r0 + wrow)*ldw + wcol, BlsW + r0*128);
    }
    __syncthreads();
    bf16x8 af[4], bfr[4];
    #pragma unroll
    for(int mf=0;mf<4;mf++) af[mf] = *(const bf16x8*)&Als[(wr*64 + mf*16 + lr)*32 + lk*8];
    #pragma unroll
    for(int nf=0;nf<4;nf++){
      const float* Bcol = BlsW + lk*8*128 + wc*64 + nf*16 + lr;
      bf16x8 bv;
      #pragma unroll
      for(int j=0;j<8;j++) bv[j] = (__bf16)Bcol[j*128];
      bfr[nf] = bv;
    }
    #pragma unroll
    for(int mf=0;mf<4;mf++)
      #pragma unroll
      for(int nf=0;nf<4;nf++)
        acc[mf][nf] = __builtin_amdgcn_mfma_f32_16x16x32_bf16(af[mf], bfr[nf], acc[mf][nf], 0,0,0);
  }

  unsigned short* C16 = (unsigned short*)Cp;
  float* C32 = (float*)Cp;
  #pragma unroll
  for(int mf=0;mf<4;mf++){
    #pragma unroll
    for(int nf=0;nf<4;nf++){
      #pragma unroll
      for(int r=0;r<4;r++){
        size_t row = (size_t)bm*128 + wr*64 + mf*16 + lk*4 + r;
        size_t col = (size_t)bn*128 + wc*64 + nf*16 + lr;
        float v = acc[mf][nf][r];
        if(mode==0){
          C16[row*ldc + col] = f2bf(v + (bias ? bias[col] : 0.f));
        } else if(mode==1){
          C16[row*ldc + col] = f2bf(gelu_tanh(v + (bias ? bias[col] : 0.f)));
        } else {
          float g = gate ? gate[col] : 1.f;
          atomicAdd(&C32[row*ldc + col], g*v);
        }
      }
    }
  }
}

// ---------------- launch ----------------

extern "C" void kernel_launch(void* const* d_in, const int* in_sizes, int n_in,
                              void* d_out, int out_size, void* d_ws, size_t ws_size,
                              hipStream_t stream){
  const float* hidden_states = (const float*)d_in[0];
  const float* enc_states    = (const float*)d_in[1];
  const float* temb          = (const float*)d_in[3];
  const float* rope_cos      = (const float*)d_in[4];
  const float* rope_sin      = (const float*)d_in[5];
  const float* w_img_mod     = (const float*)d_in[6];
  const float* b_img_mod     = (const float*)d_in[7];
  const float* w_txt_mod     = (const float*)d_in[8];
  const float* b_txt_mod     = (const float*)d_in[9];
  const float* norm_q_w      = (const float*)d_in[10];
  const float* norm_k_w      = (const float*)d_in[11];
  const float* norm_aq_w     = (const float*)d_in[12];
  const float* norm_ak_w     = (const float*)d_in[13];
  const float* w_qkv   = (const float*)d_in[14];
  const float* b_qkv   = (const float*)d_in[15];
  const float* w_aqkv  = (const float*)d_in[16];
  const float* b_aqkv  = (const float*)d_in[17];
  const float* w_out_  = (const float*)d_in[18];
  const float* b_out_  = (const float*)d_in[19];
  const float* w_aout  = (const float*)d_in[20];
  const float* b_aout  = (const float*)d_in[21];
  const float* w_mlp1i = (const float*)d_in[22];
  const float* b_mlp1i = (const float*)d_in[23];
  const float* w_mlp2i = (const float*)d_in[24];
  const float* b_mlp2i = (const float*)d_in[25];
  const float* w_mlp1t = (const float*)d_in[26];
  const float* b_mlp1t = (const float*)d_in[27];
  const float* w_mlp2t = (const float*)d_in[28];
  const float* b_mlp2t = (const float*)d_in[29];

  char* ws = (char*)d_ws;
  float* mod    = (float*)(ws + 0);                        // 2*6*3072 f32
  float* silu_t = (float*)(ws + 147456);
  unsigned short* imgm = (unsigned short*)(ws + 159744);   // 1024x3072 bf16
  unsigned short* txtm = (unsigned short*)(ws + 6451200);  // 512x3072 bf16
  float* hid = (float*)(ws + 9596928);                     // 1024x3072 f32
  float* enc = (float*)(ws + 22179840);                    // 512x3072 f32
  float* attnf = (float*)(ws + 28471296);                  // 1536x3072 f32
  unsigned short* Qb  = (unsigned short*)(ws + 47345664);  // 1536x3072 bf16
  unsigned short* Kb  = (unsigned short*)(ws + 56782848);
  unsigned short* Vb  = (unsigned short*)(ws + 66220032);  // dead after vtrans
  unsigned short* attnb = (unsigned short*)(ws + 66220032);// 1536x3072 bf16 (reuses Vb)
  unsigned short* VTb = (unsigned short*)(ws + 75657216);  // 24x128x1536 bf16
  unsigned short* Sbuf = (unsigned short*)(ws + 85094400); // 8x1536x1536 bf16 (37.7MB)
  unsigned short* qkvi = (unsigned short*)(ws + 141717504);// 1024x9216 bf16
  unsigned short* qkvt = (unsigned short*)(ws + 160591872);// 512x9216 bf16
  unsigned short* mlph = (unsigned short*)(ws + 103968768);// 1024x12288 bf16 (MLP phase; Sbuf dead)

  float* out_enc = (float*)d_out;
  float* out_hid = (float*)d_out + (size_t)STX*DIMX;

  // modulation params
  k_silu<<<12,256,0,stream>>>(temb, silu_t);
  k_modinit<<<144,256,0,stream>>>(b_img_mod, b_txt_mod, mod);
  k_modgemv<<<288,256,0,stream>>>(w_img_mod, w_txt_mod, silu_t, mod);

  // LN + modulate (mod1)
  k_lnmod<<<SIX,256,0,stream>>>(hidden_states, mod + 0,     imgm);
  k_lnmod<<<STX,256,0,stream>>>(enc_states,    mod + 18432, txtm);

  // QKV projections (weights consumed fp32 directly)
  k_gemmW<<<dim3(72,8,1),256,0,stream>>>(imgm,3072, w_qkv,9216, b_qkv,
      qkvi,9216, 3072,1, 0, nullptr);
  k_gemmW<<<dim3(72,4,1),256,0,stream>>>(txtm,3072, w_aqkv,9216, b_aqkv,
      qkvt,9216, 3072,1, 0, nullptr);

  // RMS + RoPE -> Q,K,V [1536][24][128]; V transpose
  k_rmsrope<<<dim3(1536,24),64,0,stream>>>(qkvt, qkvi, norm_q_w, norm_k_w,
      norm_aq_w, norm_ak_w, rope_cos, rope_sin, Qb, Kb, Vb);
  k_vtrans<<<dim3(24,24),256,0,stream>>>(Vb, VTb);

  // attention: 3 groups of 8 heads; PV split-K(4) atomics into attnf
  hipMemsetAsync(attnf, 0, (size_t)1536*3072*4, stream);
  for(int g=0; g<3; g++){
    long hb = g*8;
    k_gemm<<<dim3(12,12,8),256,0,stream>>>(Qb + hb*128, 3072, 128,
        Kb + hb*128, 3072, 128, nullptr,
        Sbuf, 1536, (long)1536*1536, 128,1, 0, 0.08838834764831845f, nullptr);
    k_softmax<<<8*1536,256,0,stream>>>(Sbuf);
    k_gemm<<<dim3(1,12,32),256,0,stream>>>(Sbuf, 1536, (long)1536*1536,
        VTb + (size_t)hb*128*1536, 1536, (long)128*1536, nullptr,
        attnf + hb*128, 3072, 128, 1536,4, 3, 1.f, nullptr);
  }
  // attn f32 -> bf16 for the out-proj GEMMs
  k_f2b<<<4608,256,0,stream>>>(attnf, attnb, 1536*3072/4);

  // output projections, fused residual+gate1, split-K atomics
  k_initC<<<512*3,256,0,stream>>>(enc, enc_states, mod + 18432 + 2*3072, b_aout);
  k_initC<<<1024*3,256,0,stream>>>(hid, hidden_states, mod + 2*3072, b_out_);
  k_gemmW<<<dim3(24,4,4),256,0,stream>>>(attnb,3072, w_aout,3072, nullptr,
      enc,3072, 3072,4, 3, mod + 18432 + 2*3072);
  k_gemmW<<<dim3(24,8,4),256,0,stream>>>(attnb + (size_t)512*3072,3072, w_out_,3072, nullptr,
      hid,3072, 3072,4, 3, mod + 2*3072);

  // img MLP
  k_lnmod<<<SIX,256,0,stream>>>(hid, mod + 3*3072, imgm);
  k_gemmW<<<dim3(96,8,1),256,0,stream>>>(imgm,3072, w_mlp1i,12288, b_mlp1i,
      mlph,12288, 3072,1, 1, nullptr);
  k_initC<<<1024*3,256,0,stream>>>(out_hid, hid, mod + 5*3072, b_mlp2i);
  k_gemmW<<<dim3(24,8,4),256,0,stream>>>(mlph,12288, w_mlp2i,3072, nullptr,
      out_hid,3072, 12288,4, 3, mod + 5*3072);

  // txt MLP
  k_lnmod<<<STX,256,0,stream>>>(enc, mod + 18432 + 3*3072, txtm);
  k_gemmW<<<dim3(96,4,1),256,0,stream>>>(txtm,3072, w_mlp1t,12288, b_mlp1t,
      mlph,12288, 3072,1, 1, nullptr);
  k_initC<<<512*3,256,0,stream>>>(out_enc, enc, mod + 18432 + 5*3072, b_mlp2t);
  k_gemmW<<<dim3(24,4,8),256,0,stream>>>(mlph,12288, w_mlp2t,3072, nullptr,
      out_enc,3072, 12288,8, 3, mod + 18432 + 5*3072);
}

// Round 6
// 1250.770 us; speedup vs baseline: 1.0968x; 1.0968x over previous
//
#include <hip/hip_runtime.h>

#define DIMX 3072
#define STX 512
#define SIX 1024
#define SQX 1536
#define FFX 12288

typedef __attribute__((ext_vector_type(4))) float f32x4;
typedef __attribute__((ext_vector_type(8))) __bf16 bf16x8;
typedef __attribute__((ext_vector_type(4))) int i32x4;
typedef __attribute__((ext_vector_type(4))) unsigned short u16x4;

__device__ __forceinline__ unsigned short f2bf(float f){
  unsigned u = __builtin_bit_cast(unsigned, f);
  u += 0x7FFFu + ((u>>16)&1u);
  return (unsigned short)(u>>16);
}
__device__ __forceinline__ unsigned short usbf(float x){
  return __builtin_bit_cast(unsigned short, (__bf16)x);
}
__device__ __forceinline__ float bf2f(unsigned short h){
  unsigned u = ((unsigned)h)<<16;
  return __builtin_bit_cast(float, u);
}
__device__ __forceinline__ float gelu_tanh(float x){
  float x3 = x*x*x;
  float z = 0.7978845608028654f*(x + 0.044715f*x3);
  z = fminf(fmaxf(z, -15.f), 15.f);
  float e = exp2f(z*2.8853900817779268f);   // e^(2z)
  float th = (e-1.f)/(e+1.f);
  return 0.5f*x*(1.f+th);
}

// async global->LDS, 16B per lane; lds base must be wave-uniform
__device__ __forceinline__ void gload16(const void* g, void* l){
  __builtin_amdgcn_global_load_lds(
      (const __attribute__((address_space(1))) void*)g,
      (__attribute__((address_space(3))) void*)l,
      16, 0, 0);
}

// ---------------- small kernels ----------------

__global__ void k_silu(const float* __restrict__ temb, float* __restrict__ out){
  int i = blockIdx.x*256 + threadIdx.x;
  if(i < DIMX){
    float x = temb[i];
    out[i] = x / (1.f + exp2f(-x*1.4426950408889634f));
  }
}

// mod layout: mod[mat][j][i], mat in {0=img,1=txt}, j in 0..5, i in 0..3071
__global__ void k_modinit(const float* __restrict__ b_img, const float* __restrict__ b_txt,
                          float* __restrict__ mod){
  int idx = blockIdx.x*256 + threadIdx.x;   // 0..36863
  int mat = idx / 18432; int r = idx % 18432;
  int i = r/6, j = r%6;
  const float* b = mat ? b_txt : b_img;
  mod[mat*18432 + j*3072 + i] = b[r];
}

// grid: 2 mats * 18 col-chunks * 8 k-chunks = 288 blocks of 256
__global__ void k_modgemv(const float* __restrict__ w_img, const float* __restrict__ w_txt,
                          const float* __restrict__ silu_t, float* __restrict__ mod){
  int bz = blockIdx.x;
  int ks = bz & 7; bz >>= 3;
  int nc = bz % 18; int mat = bz / 18;
  const float* W = mat ? w_txt : w_img;
  __shared__ float st[384];
  int k0 = ks*384;
  for(int i = threadIdx.x; i < 384; i += 256) st[i] = silu_t[k0+i];
  __syncthreads();
  int n0 = nc*1024 + threadIdx.x*4;
  float ax=0.f, ay=0.f, az=0.f, aw=0.f;
  const float* Wp = W + (size_t)k0*18432 + n0;
  #pragma unroll 4
  for(int k=0;k<384;k++){
    float4 w = *(const float4*)(Wp + (size_t)k*18432);
    float s = st[k];
    ax += s*w.x; ay += s*w.y; az += s*w.z; aw += s*w.w;
  }
  float* md = mod + mat*18432;
  float vals[4] = {ax, ay, az, aw};
  #pragma unroll
  for(int j=0;j<4;j++){
    int n = n0+j; int i = n/6, jj = n%6;
    atomicAdd(&md[jj*3072 + i], vals[j]);
  }
}

// out[row][col] = res[row][col] + gate[col]*bias[col]; M rows x 3072 cols
__global__ void k_initC(float* __restrict__ out, const float* __restrict__ res,
                        const float* __restrict__ gate, const float* __restrict__ bias){
  int i = (blockIdx.x*256 + threadIdx.x)*4;
  int col = i % 3072;
  float4 r = *(const float4*)(res + i);
  float4 g = *(const float4*)(gate + col);
  float4 b = *(const float4*)(bias + col);
  float4 o = {r.x + g.x*b.x, r.y + g.y*b.y, r.z + g.z*b.z, r.w + g.w*b.w};
  *(float4*)(out + i) = o;
}

// LayerNorm (no affine) + modulate: out_bf16 = (x-mu)*rstd*(scale+1) + shift
__global__ void k_lnmod(const float* __restrict__ x, const float* __restrict__ modp,
                        unsigned short* __restrict__ out){
  int row = blockIdx.x, t = threadIdx.x;
  const float* xr = x + (size_t)row*DIMX;
  float4 v0 = *(const float4*)(xr + t*4);
  float4 v1 = *(const float4*)(xr + 1024 + t*4);
  float4 v2 = *(const float4*)(xr + 2048 + t*4);
  float s  = v0.x+v0.y+v0.z+v0.w + v1.x+v1.y+v1.z+v1.w + v2.x+v2.y+v2.z+v2.w;
  float s2 = v0.x*v0.x+v0.y*v0.y+v0.z*v0.z+v0.w*v0.w
           + v1.x*v1.x+v1.y*v1.y+v1.z*v1.z+v1.w*v1.w
           + v2.x*v2.x+v2.y*v2.y+v2.z*v2.z+v2.w*v2.w;
  #pragma unroll
  for(int o=32;o>0;o>>=1){ s += __shfl_xor(s,o); s2 += __shfl_xor(s2,o); }
  __shared__ float rs_[4], rs2_[4];
  int wid = t>>6;
  if((t&63)==0){ rs_[wid]=s; rs2_[wid]=s2; }
  __syncthreads();
  float S  = rs_[0]+rs_[1]+rs_[2]+rs_[3];
  float S2 = rs2_[0]+rs2_[1]+rs2_[2]+rs2_[3];
  float mu = S*(1.f/3072.f);
  float var = S2*(1.f/3072.f) - mu*mu;
  float rstd = rsqrtf(var + 1e-6f);
  #pragma unroll
  for(int j=0;j<3;j++){
    int c = j*1024 + t*4;
    float4 sh = *(const float4*)(modp + c);
    float4 sc = *(const float4*)(modp + 3072 + c);
    float4 xv = (j==0)?v0:((j==1)?v1:v2);
    unsigned short h0 = f2bf((xv.x-mu)*rstd*(sc.x+1.f)+sh.x);
    unsigned short h1 = f2bf((xv.y-mu)*rstd*(sc.y+1.f)+sh.y);
    unsigned short h2 = f2bf((xv.z-mu)*rstd*(sc.z+1.f)+sh.z);
    unsigned short h3 = f2bf((xv.w-mu)*rstd*(sc.w+1.f)+sh.w);
    unsigned long long pk = (unsigned long long)(h0 | ((unsigned)h1<<16))
                          | ((unsigned long long)(h2 | ((unsigned)h3<<16))<<32);
    *(unsigned long long*)(out + (size_t)row*DIMX + c) = pk;
  }
}

// RMSNorm(q,k) + RoPE, V passthrough. grid (1536, 24), block 64.
__global__ void k_rmsrope(const unsigned short* __restrict__ qkv_txt,
                          const unsigned short* __restrict__ qkv_img,
                          const float* __restrict__ nqw, const float* __restrict__ nkw,
                          const float* __restrict__ naqw, const float* __restrict__ nakw,
                          const float* __restrict__ cosb, const float* __restrict__ sinb,
                          unsigned short* __restrict__ Q, unsigned short* __restrict__ K,
                          unsigned short* __restrict__ V){
  int s = blockIdx.x, h = blockIdx.y, t = threadIdx.x;
  bool txt = s < STX;
  const unsigned short* src = txt ? (qkv_txt + (size_t)s*9216)
                                  : (qkv_img + (size_t)(s-STX)*9216);
  const float* qw = txt ? naqw : nqw;
  const float* kw = txt ? nakw : nkw;
  int d0 = 2*t;
  float q1 = bf2f(src[h*128 + d0]),        q2 = bf2f(src[h*128 + d0 + 1]);
  float k1 = bf2f(src[3072 + h*128 + d0]), k2 = bf2f(src[3072 + h*128 + d0 + 1]);
  float v1 = bf2f(src[6144 + h*128 + d0]), v2 = bf2f(src[6144 + h*128 + d0 + 1]);
  float sq = q1*q1 + q2*q2, sk = k1*k1 + k2*k2;
  #pragma unroll
  for(int o=32;o>0;o>>=1){ sq += __shfl_xor(sq,o); sk += __shfl_xor(sk,o); }
  float rq = rsqrtf(sq*(1.f/128.f) + 1e-6f);
  float rk = rsqrtf(sk*(1.f/128.f) + 1e-6f);
  q1 *= rq*qw[d0]; q2 *= rq*qw[d0+1];
  k1 *= rk*kw[d0]; k2 *= rk*kw[d0+1];
  float c1 = cosb[(size_t)s*128 + d0], c2 = cosb[(size_t)s*128 + d0 + 1];
  float s1 = sinb[(size_t)s*128 + d0], s2 = sinb[(size_t)s*128 + d0 + 1];
  float Q1 = q1*c1 - q2*s1, Q2 = q2*c2 + q1*s2;
  float K1 = k1*c1 - k2*s1, K2 = k2*c2 + k1*s2;
  size_t o = ((size_t)s*24 + h)*128 + d0;
  Q[o] = f2bf(Q1); Q[o+1] = f2bf(Q2);
  K[o] = f2bf(K1); K[o+1] = f2bf(K2);
  V[o] = f2bf(v1); V[o+1] = f2bf(v2);
}

// V[s][h][d] -> VT[h][d][s]. grid (24 s-tiles, 24 heads), block 256.
__global__ void k_vtrans(const unsigned short* __restrict__ V, unsigned short* __restrict__ VT){
  __shared__ unsigned short tile[64][136];
  int st = blockIdx.x, h = blockIdx.y, t = threadIdx.x;
  int s0 = st*64;
  {
    int s = t>>2;
    #pragma unroll
    for(int i=0;i<4;i++){
      int oct = ((t&3)<<2) + i;     // 0..15
      i32x4 d = *(const i32x4*)(V + ((size_t)(s0+s)*24 + h)*128 + oct*8);
      *(i32x4*)&tile[s][oct*8] = d;
    }
  }
  __syncthreads();
  {
    int d0 = t>>3; int strip = t&7;
    #pragma unroll
    for(int i=0;i<4;i++){
      int d = d0 + i*32;
      unsigned short h8[8];
      #pragma unroll
      for(int j=0;j<8;j++) h8[j] = tile[strip*8 + j][d];
      unsigned a0 = h8[0] | ((unsigned)h8[1]<<16);
      unsigned a1 = h8[2] | ((unsigned)h8[3]<<16);
      unsigned a2 = h8[4] | ((unsigned)h8[5]<<16);
      unsigned a3 = h8[6] | ((unsigned)h8[7]<<16);
      i32x4 dv = {(int)a0,(int)a1,(int)a2,(int)a3};
      *(i32x4*)(VT + ((size_t)h*128 + d)*1536 + s0 + strip*8) = dv;
    }
  }
}

// ---------------- fused flash attention ----------------
// grid (12 q-blocks, 24 heads), 256 threads (4 waves); each wave owns 32 q rows.
// Q/K: [1536][24][128] bf16; VT: [24][128][1536] bf16; O(attnb): [1536][3072] bf16
__global__ __launch_bounds__(256,2) void k_fattn(
    const unsigned short* __restrict__ Q,
    const unsigned short* __restrict__ Kb,
    const unsigned short* __restrict__ VT,
    unsigned short* __restrict__ O)
{
  __shared__ unsigned short Kls[4][64][32];   // d-chunked K tile [kv=64][d=128]
  __shared__ unsigned short Vls[2][128][32];  // kv-chunked VT tile [d=128][kv=64]
  __shared__ unsigned short Pls[128][72];     // P tile, padded rows
  const int t = threadIdx.x;
  const int qb = blockIdx.x, h = blockIdx.y;
  const int lane = t&63, w = t>>6;
  const int lr = lane&15, lk = lane>>4;
  const float SC  = 0.08838834764831845f;
  const float L2E = 1.4426950408889634f;

  // Q fragments in registers (A-layout: row = mf*16+lr, k = ks*32+lk*8)
  bf16x8 qf[2][4];
  {
    const unsigned short* qp = Q + ((size_t)(qb*128 + w*32 + lr)*3072) + h*128 + lk*8;
    #pragma unroll
    for(int mf=0;mf<2;mf++)
      #pragma unroll
      for(int ks=0;ks<4;ks++)
        qf[mf][ks] = *(const bf16x8*)(qp + (size_t)mf*16*3072 + ks*32);
  }

  f32x4 o[2][8];
  #pragma unroll
  for(int i=0;i<2;i++)
    #pragma unroll
    for(int j=0;j<8;j++) o[i][j] = (f32x4){0.f,0.f,0.f,0.f};
  float mrow[2][4], lrow[2][4];
  #pragma unroll
  for(int i=0;i<2;i++)
    #pragma unroll
    for(int r=0;r<4;r++){ mrow[i][r] = -3.0e30f; lrow[i][r] = 0.f; }

  for(int kv0=0; kv0<SQX; kv0+=64){
    __syncthreads();
    { // stage K tile: wave w handles d-chunk w; 4 issues of 16 kv rows
      const unsigned short* kp = Kb + ((size_t)(kv0 + (lane>>2))*3072) + h*128 + w*32 + (lane&3)*8;
      #pragma unroll
      for(int i=0;i<4;i++)
        gload16(kp + (size_t)i*16*3072, &Kls[w][i*16][0]);
    }
    { // stage VT tile: wave w handles (kv-chunk w>>1, d-rows (w&1)*64 .. +64)
      int c = w>>1;
      const unsigned short* vp = VT + ((size_t)(h*128 + (w&1)*64 + (lane>>2)))*1536 + kv0 + c*32 + (lane&3)*8;
      #pragma unroll
      for(int j=0;j<4;j++)
        gload16(vp + (size_t)j*16*1536, &Vls[c][(w&1)*64 + j*16][0]);
    }
    __syncthreads();

    // QK^T -> s[2][4] (rows mf*16+lk*4+r, cols nf*16+lr)
    f32x4 s[2][4];
    #pragma unroll
    for(int mf=0;mf<2;mf++)
      #pragma unroll
      for(int nf=0;nf<4;nf++) s[mf][nf] = (f32x4){0.f,0.f,0.f,0.f};
    #pragma unroll
    for(int ks=0;ks<4;ks++){
      bf16x8 kf[4];
      #pragma unroll
      for(int nf=0;nf<4;nf++) kf[nf] = *(const bf16x8*)&Kls[ks][nf*16+lr][lk*8];
      #pragma unroll
      for(int mf=0;mf<2;mf++)
        #pragma unroll
        for(int nf=0;nf<4;nf++)
          s[mf][nf] = __builtin_amdgcn_mfma_f32_16x16x32_bf16(qf[mf][ks], kf[nf], s[mf][nf], 0,0,0);
    }

    // online softmax (row-wise over 64 kv; reduce over lr lanes)
    #pragma unroll
    for(int mf=0;mf<2;mf++){
      #pragma unroll
      for(int r=0;r<4;r++){
        float v = fmaxf(fmaxf(s[mf][0][r], s[mf][1][r]), fmaxf(s[mf][2][r], s[mf][3][r]));
        #pragma unroll
        for(int d=1; d<16; d<<=1) v = fmaxf(v, __shfl_xor(v, d));
        float nm = fmaxf(mrow[mf][r], v*SC);
        float fac = exp2f((mrow[mf][r]-nm)*L2E);
        mrow[mf][r] = nm;
        float rs = 0.f;
        #pragma unroll
        for(int nf=0;nf<4;nf++){
          float p = exp2f((s[mf][nf][r]*SC - nm)*L2E);
          s[mf][nf][r] = p;
          rs += p;
        }
        #pragma unroll
        for(int d=1; d<16; d<<=1) rs += __shfl_xor(rs, d);
        lrow[mf][r] = lrow[mf][r]*fac + rs;
        #pragma unroll
        for(int nf=0;nf<8;nf++) o[mf][nf][r] *= fac;
      }
    }

    // P -> LDS (bf16), rows are this wave's own 32 q rows
    #pragma unroll
    for(int mf=0;mf<2;mf++)
      #pragma unroll
      for(int nf=0;nf<4;nf++)
        #pragma unroll
        for(int r=0;r<4;r++)
          Pls[w*32 + mf*16 + lk*4 + r][nf*16 + lr] = usbf(s[mf][nf][r]);

    // PV: o += P[128q x 64kv] @ V[64kv x 128d]
    #pragma unroll
    for(int ks2=0; ks2<2; ks2++){
      bf16x8 pa[2];
      #pragma unroll
      for(int mf=0;mf<2;mf++)
        pa[mf] = *(const bf16x8*)&Pls[w*32 + mf*16 + lr][ks2*32 + lk*8];
      #pragma unroll
      for(int nf=0;nf<8;nf++){
        bf16x8 vf = *(const bf16x8*)&Vls[ks2][nf*16+lr][lk*8];
        #pragma unroll
        for(int mf=0;mf<2;mf++)
          o[mf][nf] = __builtin_amdgcn_mfma_f32_16x16x32_bf16(pa[mf], vf, o[mf][nf], 0,0,0);
      }
    }
  }

  // epilogue: normalize, write bf16
  #pragma unroll
  for(int mf=0;mf<2;mf++){
    float inv[4];
    #pragma unroll
    for(int r=0;r<4;r++) inv[r] = 1.f/lrow[mf][r];
    #pragma unroll
    for(int nf=0;nf<8;nf++){
      #pragma unroll
      for(int r=0;r<4;r++){
        size_t row = (size_t)qb*128 + w*32 + mf*16 + lk*4 + r;
        size_t col = (size_t)h*128 + nf*16 + lr;
        O[row*3072 + col] = usbf(o[mf][nf][r]*inv[r]);
      }
    }
  }
}

// ---------------- MFMA GEMM, bf16 A, fp32 W[K][N] (weights, JIT convert) ----
// C[M,N] = epilogue(A[M,K] @ W[K][N] + bias)
// mode 0: bf16 out (+bias)   mode 1: gelu(v+bias) -> bf16
// mode 3: atomicAdd(C_f32, (gate?gate[col]:1) * acc)   [bias via k_initC]
__global__ __launch_bounds__(256,4) void k_gemmW(
    const unsigned short* __restrict__ A, long lda,
    const float* __restrict__ W, long ldw,
    const float* __restrict__ bias,
    void* __restrict__ Cp, long ldc,
    int K, int KS, int mode,
    const float* __restrict__ gate)
{
  __shared__ unsigned short Als[128*32];   // 8 KB
  __shared__ float Wls[32*128];            // 16 KB
  __shared__ unsigned short Bls[128*40];   // 10 KB, padded bf16 B^T tile
  const int t = threadIdx.x;
  const int bn = blockIdx.x, bm = blockIdx.y;
  const int zs = blockIdx.z;
  const int Kc = K / KS, kbeg = zs*Kc, kend = kbeg + Kc;

  const unsigned short* Ab = A + (size_t)bm*128*lda;
  const float* Wb = W + (size_t)bn*128;

  const int lane = t & 63, wid = t>>6, wr = wid>>1, wc = wid&1;
  const int lr = lane & 15, lk = lane>>4;
  const int srow = (lane>>2);
  const int soff = (lane&3)*8;
  const int wrow = (lane>>5);        // W staging: row within pair
  const int wcol = (lane&31)*4;      // W staging: 4-float chunk
  const int ck = (t&7)*4;            // convert: k base
  const int cn = (t>>3)*4;           // convert: n base

  f32x4 acc[4][4];
  #pragma unroll
  for(int i=0;i<4;i++)
    #pragma unroll
    for(int j=0;j<4;j++) acc[i][j] = {0.f,0.f,0.f,0.f};

  for(int k0=kbeg; k0<kend; k0+=32){
    __syncthreads();
    // A: 128 rows x 32 bf16 (linear LDS)
    gload16(Ab + (size_t)(     wid*16 + srow)*lda + k0 + soff, Als + (     wid*16)*32);
    gload16(Ab + (size_t)(64 + wid*16 + srow)*lda + k0 + soff, Als + (64 + wid*16)*32);
    // W: 32 k-rows x 128 f32 (linear LDS)
    #pragma unroll
    for(int i=0;i<4;i++){
      int r0 = wid*8 + i*2;
      gload16(Wb + (size_t)(k0 + r0 + wrow)*ldw + wcol, Wls + r0*128);
    }
    __syncthreads();
    // convert Wls[32][128] f32 -> Bls[128][40] bf16 (B^T tile)
    {
      f32x4 r0 = *(const f32x4*)&Wls[(ck+0)*128 + cn];
      f32x4 r1 = *(const f32x4*)&Wls[(ck+1)*128 + cn];
      f32x4 r2 = *(const f32x4*)&Wls[(ck+2)*128 + cn];
      f32x4 r3 = *(const f32x4*)&Wls[(ck+3)*128 + cn];
      #pragma unroll
      for(int jn=0;jn<4;jn++){
        u16x4 pk = { usbf(r0[jn]), usbf(r1[jn]), usbf(r2[jn]), usbf(r3[jn]) };
        *(u16x4*)&Bls[(cn+jn)*40 + ck] = pk;
      }
    }
    __syncthreads();
    bf16x8 af[4], bfr[4];
    #pragma unroll
    for(int mf=0;mf<4;mf++) af[mf]  = *(const bf16x8*)&Als[(wr*64 + mf*16 + lr)*32 + lk*8];
    #pragma unroll
    for(int nf=0;nf<4;nf++) bfr[nf] = *(const bf16x8*)&Bls[(wc*64 + nf*16 + lr)*40 + lk*8];
    #pragma unroll
    for(int mf=0;mf<4;mf++)
      #pragma unroll
      for(int nf=0;nf<4;nf++)
        acc[mf][nf] = __builtin_amdgcn_mfma_f32_16x16x32_bf16(af[mf], bfr[nf], acc[mf][nf], 0,0,0);
  }

  unsigned short* C16 = (unsigned short*)Cp;
  float* C32 = (float*)Cp;
  #pragma unroll
  for(int mf=0;mf<4;mf++){
    #pragma unroll
    for(int nf=0;nf<4;nf++){
      #pragma unroll
      for(int r=0;r<4;r++){
        size_t row = (size_t)bm*128 + wr*64 + mf*16 + lk*4 + r;
        size_t col = (size_t)bn*128 + wc*64 + nf*16 + lr;
        float v = acc[mf][nf][r];
        if(mode==0){
          C16[row*ldc + col] = f2bf(v + (bias ? bias[col] : 0.f));
        } else if(mode==1){
          C16[row*ldc + col] = f2bf(gelu_tanh(v + (bias ? bias[col] : 0.f)));
        } else {
          float g = gate ? gate[col] : 1.f;
          atomicAdd(&C32[row*ldc + col], g*v);
        }
      }
    }
  }
}

// ---------------- launch ----------------

extern "C" void kernel_launch(void* const* d_in, const int* in_sizes, int n_in,
                              void* d_out, int out_size, void* d_ws, size_t ws_size,
                              hipStream_t stream){
  const float* hidden_states = (const float*)d_in[0];
  const float* enc_states    = (const float*)d_in[1];
  const float* temb          = (const float*)d_in[3];
  const float* rope_cos      = (const float*)d_in[4];
  const float* rope_sin      = (const float*)d_in[5];
  const float* w_img_mod     = (const float*)d_in[6];
  const float* b_img_mod     = (const float*)d_in[7];
  const float* w_txt_mod     = (const float*)d_in[8];
  const float* b_txt_mod     = (const float*)d_in[9];
  const float* norm_q_w      = (const float*)d_in[10];
  const float* norm_k_w      = (const float*)d_in[11];
  const float* norm_aq_w     = (const float*)d_in[12];
  const float* norm_ak_w     = (const float*)d_in[13];
  const float* w_qkv   = (const float*)d_in[14];
  const float* b_qkv   = (const float*)d_in[15];
  const float* w_aqkv  = (const float*)d_in[16];
  const float* b_aqkv  = (const float*)d_in[17];
  const float* w_out_  = (const float*)d_in[18];
  const float* b_out_  = (const float*)d_in[19];
  const float* w_aout  = (const float*)d_in[20];
  const float* b_aout  = (const float*)d_in[21];
  const float* w_mlp1i = (const float*)d_in[22];
  const float* b_mlp1i = (const float*)d_in[23];
  const float* w_mlp2i = (const float*)d_in[24];
  const float* b_mlp2i = (const float*)d_in[25];
  const float* w_mlp1t = (const float*)d_in[26];
  const float* b_mlp1t = (const float*)d_in[27];
  const float* w_mlp2t = (const float*)d_in[28];
  const float* b_mlp2t = (const float*)d_in[29];

  char* ws = (char*)d_ws;
  float* mod    = (float*)(ws + 0);                        // 2*6*3072 f32
  float* silu_t = (float*)(ws + 147456);
  unsigned short* imgm = (unsigned short*)(ws + 159744);   // 1024x3072 bf16
  unsigned short* txtm = (unsigned short*)(ws + 6451200);  // 512x3072 bf16
  float* hid = (float*)(ws + 9596928);                     // 1024x3072 f32
  float* enc = (float*)(ws + 22179840);                    // 512x3072 f32
  unsigned short* Qb  = (unsigned short*)(ws + 47345664);  // 1536x3072 bf16
  unsigned short* Kb  = (unsigned short*)(ws + 56782848);
  unsigned short* Vb  = (unsigned short*)(ws + 66220032);  // dead after vtrans
  unsigned short* attnb = (unsigned short*)(ws + 66220032);// 1536x3072 bf16 (reuses Vb)
  unsigned short* VTb = (unsigned short*)(ws + 75657216);  // 24x128x1536 bf16
  unsigned short* qkvi = (unsigned short*)(ws + 141717504);// 1024x9216 bf16
  unsigned short* qkvt = (unsigned short*)(ws + 160591872);// 512x9216 bf16
  unsigned short* mlph = (unsigned short*)(ws + 103968768);// 1024x12288 bf16

  float* out_enc = (float*)d_out;
  float* out_hid = (float*)d_out + (size_t)STX*DIMX;

  // modulation params
  k_silu<<<12,256,0,stream>>>(temb, silu_t);
  k_modinit<<<144,256,0,stream>>>(b_img_mod, b_txt_mod, mod);
  k_modgemv<<<288,256,0,stream>>>(w_img_mod, w_txt_mod, silu_t, mod);

  // LN + modulate (mod1)
  k_lnmod<<<SIX,256,0,stream>>>(hidden_states, mod + 0,     imgm);
  k_lnmod<<<STX,256,0,stream>>>(enc_states,    mod + 18432, txtm);

  // QKV projections (weights consumed fp32 directly)
  k_gemmW<<<dim3(72,8,1),256,0,stream>>>(imgm,3072, w_qkv,9216, b_qkv,
      qkvi,9216, 3072,1, 0, nullptr);
  k_gemmW<<<dim3(72,4,1),256,0,stream>>>(txtm,3072, w_aqkv,9216, b_aqkv,
      qkvt,9216, 3072,1, 0, nullptr);

  // RMS + RoPE -> Q,K,V [1536][24][128]; V transpose
  k_rmsrope<<<dim3(1536,24),64,0,stream>>>(qkvt, qkvi, norm_q_w, norm_k_w,
      norm_aq_w, norm_ak_w, rope_cos, rope_sin, Qb, Kb, Vb);
  k_vtrans<<<dim3(24,24),256,0,stream>>>(Vb, VTb);

  // fused flash attention -> attnb bf16
  k_fattn<<<dim3(12,24),256,0,stream>>>(Qb, Kb, VTb, attnb);

  // output projections, fused residual+gate1, split-K atomics
  k_initC<<<512*3,256,0,stream>>>(enc, enc_states, mod + 18432 + 2*3072, b_aout);
  k_initC<<<1024*3,256,0,stream>>>(hid, hidden_states, mod + 2*3072, b_out_);
  k_gemmW<<<dim3(24,4,8),256,0,stream>>>(attnb,3072, w_aout,3072, nullptr,
      enc,3072, 3072,8, 3, mod + 18432 + 2*3072);
  k_gemmW<<<dim3(24,8,4),256,0,stream>>>(attnb + (size_t)512*3072,3072, w_out_,3072, nullptr,
      hid,3072, 3072,4, 3, mod + 2*3072);

  // img MLP
  k_lnmod<<<SIX,256,0,stream>>>(hid, mod + 3*3072, imgm);
  k_gemmW<<<dim3(96,8,1),256,0,stream>>>(imgm,3072, w_mlp1i,12288, b_mlp1i,
      mlph,12288, 3072,1, 1, nullptr);
  k_initC<<<1024*3,256,0,stream>>>(out_hid, hid, mod + 5*3072, b_mlp2i);
  k_gemmW<<<dim3(24,8,4),256,0,stream>>>(mlph,12288, w_mlp2i,3072, nullptr,
      out_hid,3072, 12288,4, 3, mod + 5*3072);

  // txt MLP
  k_lnmod<<<STX,256,0,stream>>>(enc, mod + 18432 + 3*3072, txtm);
  k_gemmW<<<dim3(96,4,1),256,0,stream>>>(txtm,3072, w_mlp1t,12288, b_mlp1t,
      mlph,12288, 3072,1, 1, nullptr);
  k_initC<<<512*3,256,0,stream>>>(out_enc, enc, mod + 18432 + 5*3072, b_mlp2t);
  k_gemmW<<<dim3(24,4,8),256,0,stream>>>(mlph,12288, w_mlp2t,3072, nullptr,
      out_enc,3072, 12288,8, 3, mod + 18432 + 5*3072);
}

// Round 7
// 1194.995 us; speedup vs baseline: 1.1480x; 1.0467x over previous
//
#include <hip/hip_runtime.h>

#define DIMX 3072
#define STX 512
#define SIX 1024
#define SQX 1536
#define FFX 12288

typedef __attribute__((ext_vector_type(4))) float f32x4;
typedef __attribute__((ext_vector_type(8))) __bf16 bf16x8;
typedef __attribute__((ext_vector_type(4))) int i32x4;
typedef __attribute__((ext_vector_type(4))) unsigned short u16x4;

__device__ __forceinline__ unsigned short f2bf(float f){
  unsigned u = __builtin_bit_cast(unsigned, f);
  u += 0x7FFFu + ((u>>16)&1u);
  return (unsigned short)(u>>16);
}
__device__ __forceinline__ unsigned short usbf(float x){
  return __builtin_bit_cast(unsigned short, (__bf16)x);
}
__device__ __forceinline__ float bf2f(unsigned short h){
  unsigned u = ((unsigned)h)<<16;
  return __builtin_bit_cast(float, u);
}
__device__ __forceinline__ float gelu_tanh(float x){
  float x3 = x*x*x;
  float z = 0.7978845608028654f*(x + 0.044715f*x3);
  z = fminf(fmaxf(z, -15.f), 15.f);
  float e = exp2f(z*2.8853900817779268f);   // e^(2z)
  float th = (e-1.f)/(e+1.f);
  return 0.5f*x*(1.f+th);
}

// async global->LDS, 16B per lane; lds base must be wave-uniform
__device__ __forceinline__ void gload16(const void* g, void* l){
  __builtin_amdgcn_global_load_lds(
      (const __attribute__((address_space(1))) void*)g,
      (__attribute__((address_space(3))) void*)l,
      16, 0, 0);
}

// ---------------- small kernels ----------------

__global__ void k_silu(const float* __restrict__ temb, float* __restrict__ out){
  int i = blockIdx.x*256 + threadIdx.x;
  if(i < DIMX){
    float x = temb[i];
    out[i] = x / (1.f + exp2f(-x*1.4426950408889634f));
  }
}

// mod layout: mod[mat][j][i], mat in {0=img,1=txt}, j in 0..5, i in 0..3071
__global__ void k_modinit(const float* __restrict__ b_img, const float* __restrict__ b_txt,
                          float* __restrict__ mod){
  int idx = blockIdx.x*256 + threadIdx.x;   // 0..36863
  int mat = idx / 18432; int r = idx % 18432;
  int i = r/6, j = r%6;
  const float* b = mat ? b_txt : b_img;
  mod[mat*18432 + j*3072 + i] = b[r];
}

// grid: 2 mats * 18 col-chunks * 8 k-chunks = 288 blocks of 256
__global__ void k_modgemv(const float* __restrict__ w_img, const float* __restrict__ w_txt,
                          const float* __restrict__ silu_t, float* __restrict__ mod){
  int bz = blockIdx.x;
  int ks = bz & 7; bz >>= 3;
  int nc = bz % 18; int mat = bz / 18;
  const float* W = mat ? w_txt : w_img;
  __shared__ float st[384];
  int k0 = ks*384;
  for(int i = threadIdx.x; i < 384; i += 256) st[i] = silu_t[k0+i];
  __syncthreads();
  int n0 = nc*1024 + threadIdx.x*4;
  float ax=0.f, ay=0.f, az=0.f, aw=0.f;
  const float* Wp = W + (size_t)k0*18432 + n0;
  #pragma unroll 4
  for(int k=0;k<384;k++){
    float4 w = *(const float4*)(Wp + (size_t)k*18432);
    float s = st[k];
    ax += s*w.x; ay += s*w.y; az += s*w.z; aw += s*w.w;
  }
  float* md = mod + mat*18432;
  float vals[4] = {ax, ay, az, aw};
  #pragma unroll
  for(int j=0;j<4;j++){
    int n = n0+j; int i = n/6, jj = n%6;
    atomicAdd(&md[jj*3072 + i], vals[j]);
  }
}

// out[row][col] = res[row][col] + gate[col]*bias[col]; M rows x 3072 cols
__global__ void k_initC(float* __restrict__ out, const float* __restrict__ res,
                        const float* __restrict__ gate, const float* __restrict__ bias){
  int i = (blockIdx.x*256 + threadIdx.x)*4;
  int col = i % 3072;
  float4 r = *(const float4*)(res + i);
  float4 g = *(const float4*)(gate + col);
  float4 b = *(const float4*)(bias + col);
  float4 o = {r.x + g.x*b.x, r.y + g.y*b.y, r.z + g.z*b.z, r.w + g.w*b.w};
  *(float4*)(out + i) = o;
}

// LayerNorm (no affine) + modulate: out_bf16 = (x-mu)*rstd*(scale+1) + shift
__global__ void k_lnmod(const float* __restrict__ x, const float* __restrict__ modp,
                        unsigned short* __restrict__ out){
  int row = blockIdx.x, t = threadIdx.x;
  const float* xr = x + (size_t)row*DIMX;
  float4 v0 = *(const float4*)(xr + t*4);
  float4 v1 = *(const float4*)(xr + 1024 + t*4);
  float4 v2 = *(const float4*)(xr + 2048 + t*4);
  float s  = v0.x+v0.y+v0.z+v0.w + v1.x+v1.y+v1.z+v1.w + v2.x+v2.y+v2.z+v2.w;
  float s2 = v0.x*v0.x+v0.y*v0.y+v0.z*v0.z+v0.w*v0.w
           + v1.x*v1.x+v1.y*v1.y+v1.z*v1.z+v1.w*v1.w
           + v2.x*v2.x+v2.y*v2.y+v2.z*v2.z+v2.w*v2.w;
  #pragma unroll
  for(int o=32;o>0;o>>=1){ s += __shfl_xor(s,o); s2 += __shfl_xor(s2,o); }
  __shared__ float rs_[4], rs2_[4];
  int wid = t>>6;
  if((t&63)==0){ rs_[wid]=s; rs2_[wid]=s2; }
  __syncthreads();
  float S  = rs_[0]+rs_[1]+rs_[2]+rs_[3];
  float S2 = rs2_[0]+rs2_[1]+rs2_[2]+rs2_[3];
  float mu = S*(1.f/3072.f);
  float var = S2*(1.f/3072.f) - mu*mu;
  float rstd = rsqrtf(var + 1e-6f);
  #pragma unroll
  for(int j=0;j<3;j++){
    int c = j*1024 + t*4;
    float4 sh = *(const float4*)(modp + c);
    float4 sc = *(const float4*)(modp + 3072 + c);
    float4 xv = (j==0)?v0:((j==1)?v1:v2);
    unsigned short h0 = f2bf((xv.x-mu)*rstd*(sc.x+1.f)+sh.x);
    unsigned short h1 = f2bf((xv.y-mu)*rstd*(sc.y+1.f)+sh.y);
    unsigned short h2 = f2bf((xv.z-mu)*rstd*(sc.z+1.f)+sh.z);
    unsigned short h3 = f2bf((xv.w-mu)*rstd*(sc.w+1.f)+sh.w);
    unsigned long long pk = (unsigned long long)(h0 | ((unsigned)h1<<16))
                          | ((unsigned long long)(h2 | ((unsigned)h3<<16))<<32);
    *(unsigned long long*)(out + (size_t)row*DIMX + c) = pk;
  }
}

// RMSNorm(q,k) + RoPE, V passthrough. grid (1536, 24), block 64.
__global__ void k_rmsrope(const unsigned short* __restrict__ qkv_txt,
                          const unsigned short* __restrict__ qkv_img,
                          const float* __restrict__ nqw, const float* __restrict__ nkw,
                          const float* __restrict__ naqw, const float* __restrict__ nakw,
                          const float* __restrict__ cosb, const float* __restrict__ sinb,
                          unsigned short* __restrict__ Q, unsigned short* __restrict__ K,
                          unsigned short* __restrict__ V){
  int s = blockIdx.x, h = blockIdx.y, t = threadIdx.x;
  bool txt = s < STX;
  const unsigned short* src = txt ? (qkv_txt + (size_t)s*9216)
                                  : (qkv_img + (size_t)(s-STX)*9216);
  const float* qw = txt ? naqw : nqw;
  const float* kw = txt ? nakw : nkw;
  int d0 = 2*t;
  float q1 = bf2f(src[h*128 + d0]),        q2 = bf2f(src[h*128 + d0 + 1]);
  float k1 = bf2f(src[3072 + h*128 + d0]), k2 = bf2f(src[3072 + h*128 + d0 + 1]);
  float v1 = bf2f(src[6144 + h*128 + d0]), v2 = bf2f(src[6144 + h*128 + d0 + 1]);
  float sq = q1*q1 + q2*q2, sk = k1*k1 + k2*k2;
  #pragma unroll
  for(int o=32;o>0;o>>=1){ sq += __shfl_xor(sq,o); sk += __shfl_xor(sk,o); }
  float rq = rsqrtf(sq*(1.f/128.f) + 1e-6f);
  float rk = rsqrtf(sk*(1.f/128.f) + 1e-6f);
  q1 *= rq*qw[d0]; q2 *= rq*qw[d0+1];
  k1 *= rk*kw[d0]; k2 *= rk*kw[d0+1];
  float c1 = cosb[(size_t)s*128 + d0], c2 = cosb[(size_t)s*128 + d0 + 1];
  float s1 = sinb[(size_t)s*128 + d0], s2 = sinb[(size_t)s*128 + d0 + 1];
  float Q1 = q1*c1 - q2*s1, Q2 = q2*c2 + q1*s2;
  float K1 = k1*c1 - k2*s1, K2 = k2*c2 + k1*s2;
  size_t o = ((size_t)s*24 + h)*128 + d0;
  Q[o] = f2bf(Q1); Q[o+1] = f2bf(Q2);
  K[o] = f2bf(K1); K[o+1] = f2bf(K2);
  V[o] = f2bf(v1); V[o+1] = f2bf(v2);
}

// V[s][h][d] -> VT[h][d][s]. grid (24 s-tiles, 24 heads), block 256.
__global__ void k_vtrans(const unsigned short* __restrict__ V, unsigned short* __restrict__ VT){
  __shared__ unsigned short tile[64][136];
  int st = blockIdx.x, h = blockIdx.y, t = threadIdx.x;
  int s0 = st*64;
  {
    int s = t>>2;
    #pragma unroll
    for(int i=0;i<4;i++){
      int oct = ((t&3)<<2) + i;     // 0..15
      i32x4 d = *(const i32x4*)(V + ((size_t)(s0+s)*24 + h)*128 + oct*8);
      *(i32x4*)&tile[s][oct*8] = d;
    }
  }
  __syncthreads();
  {
    int d0 = t>>3; int strip = t&7;
    #pragma unroll
    for(int i=0;i<4;i++){
      int d = d0 + i*32;
      unsigned short h8[8];
      #pragma unroll
      for(int j=0;j<8;j++) h8[j] = tile[strip*8 + j][d];
      unsigned a0 = h8[0] | ((unsigned)h8[1]<<16);
      unsigned a1 = h8[2] | ((unsigned)h8[3]<<16);
      unsigned a2 = h8[4] | ((unsigned)h8[5]<<16);
      unsigned a3 = h8[6] | ((unsigned)h8[7]<<16);
      i32x4 dv = {(int)a0,(int)a1,(int)a2,(int)a3};
      *(i32x4*)(VT + ((size_t)h*128 + d)*1536 + s0 + strip*8) = dv;
    }
  }
}

// ---------------- fused flash attention ----------------
// grid (12 q-blocks, 24 heads), 256 threads (4 waves); each wave owns 32 q rows.
__global__ __launch_bounds__(256,2) void k_fattn(
    const unsigned short* __restrict__ Q,
    const unsigned short* __restrict__ Kb,
    const unsigned short* __restrict__ VT,
    unsigned short* __restrict__ O)
{
  __shared__ unsigned short Kls[4][64][32];   // d-chunked K tile [kv=64][d=128]
  __shared__ unsigned short Vls[2][128][32];  // kv-chunked VT tile [d=128][kv=64]
  __shared__ unsigned short Pls[128][72];     // P tile, padded rows
  const int t = threadIdx.x;
  const int qb = blockIdx.x, h = blockIdx.y;
  const int lane = t&63, w = t>>6;
  const int lr = lane&15, lk = lane>>4;
  const float SC  = 0.08838834764831845f;
  const float L2E = 1.4426950408889634f;

  bf16x8 qf[2][4];
  {
    const unsigned short* qp = Q + ((size_t)(qb*128 + w*32 + lr)*3072) + h*128 + lk*8;
    #pragma unroll
    for(int mf=0;mf<2;mf++)
      #pragma unroll
      for(int ks=0;ks<4;ks++)
        qf[mf][ks] = *(const bf16x8*)(qp + (size_t)mf*16*3072 + ks*32);
  }

  f32x4 o[2][8];
  #pragma unroll
  for(int i=0;i<2;i++)
    #pragma unroll
    for(int j=0;j<8;j++) o[i][j] = (f32x4){0.f,0.f,0.f,0.f};
  float mrow[2][4], lrow[2][4];
  #pragma unroll
  for(int i=0;i<2;i++)
    #pragma unroll
    for(int r=0;r<4;r++){ mrow[i][r] = -3.0e30f; lrow[i][r] = 0.f; }

  for(int kv0=0; kv0<SQX; kv0+=64){
    __syncthreads();
    {
      const unsigned short* kp = Kb + ((size_t)(kv0 + (lane>>2))*3072) + h*128 + w*32 + (lane&3)*8;
      #pragma unroll
      for(int i=0;i<4;i++)
        gload16(kp + (size_t)i*16*3072, &Kls[w][i*16][0]);
    }
    {
      int c = w>>1;
      const unsigned short* vp = VT + ((size_t)(h*128 + (w&1)*64 + (lane>>2)))*1536 + kv0 + c*32 + (lane&3)*8;
      #pragma unroll
      for(int j=0;j<4;j++)
        gload16(vp + (size_t)j*16*1536, &Vls[c][(w&1)*64 + j*16][0]);
    }
    __syncthreads();

    f32x4 s[2][4];
    #pragma unroll
    for(int mf=0;mf<2;mf++)
      #pragma unroll
      for(int nf=0;nf<4;nf++) s[mf][nf] = (f32x4){0.f,0.f,0.f,0.f};
    #pragma unroll
    for(int ks=0;ks<4;ks++){
      bf16x8 kf[4];
      #pragma unroll
      for(int nf=0;nf<4;nf++) kf[nf] = *(const bf16x8*)&Kls[ks][nf*16+lr][lk*8];
      #pragma unroll
      for(int mf=0;mf<2;mf++)
        #pragma unroll
        for(int nf=0;nf<4;nf++)
          s[mf][nf] = __builtin_amdgcn_mfma_f32_16x16x32_bf16(qf[mf][ks], kf[nf], s[mf][nf], 0,0,0);
    }

    #pragma unroll
    for(int mf=0;mf<2;mf++){
      #pragma unroll
      for(int r=0;r<4;r++){
        float v = fmaxf(fmaxf(s[mf][0][r], s[mf][1][r]), fmaxf(s[mf][2][r], s[mf][3][r]));
        #pragma unroll
        for(int d=1; d<16; d<<=1) v = fmaxf(v, __shfl_xor(v, d));
        float nm = fmaxf(mrow[mf][r], v*SC);
        float fac = exp2f((mrow[mf][r]-nm)*L2E);
        mrow[mf][r] = nm;
        float rs = 0.f;
        #pragma unroll
        for(int nf=0;nf<4;nf++){
          float p = exp2f((s[mf][nf][r]*SC - nm)*L2E);
          s[mf][nf][r] = p;
          rs += p;
        }
        #pragma unroll
        for(int d=1; d<16; d<<=1) rs += __shfl_xor(rs, d);
        lrow[mf][r] = lrow[mf][r]*fac + rs;
        #pragma unroll
        for(int nf=0;nf<8;nf++) o[mf][nf][r] *= fac;
      }
    }

    #pragma unroll
    for(int mf=0;mf<2;mf++)
      #pragma unroll
      for(int nf=0;nf<4;nf++)
        #pragma unroll
        for(int r=0;r<4;r++)
          Pls[w*32 + mf*16 + lk*4 + r][nf*16 + lr] = usbf(s[mf][nf][r]);

    #pragma unroll
    for(int ks2=0; ks2<2; ks2++){
      bf16x8 pa[2];
      #pragma unroll
      for(int mf=0;mf<2;mf++)
        pa[mf] = *(const bf16x8*)&Pls[w*32 + mf*16 + lr][ks2*32 + lk*8];
      #pragma unroll
      for(int nf=0;nf<8;nf++){
        bf16x8 vf = *(const bf16x8*)&Vls[ks2][nf*16+lr][lk*8];
        #pragma unroll
        for(int mf=0;mf<2;mf++)
          o[mf][nf] = __builtin_amdgcn_mfma_f32_16x16x32_bf16(pa[mf], vf, o[mf][nf], 0,0,0);
      }
    }
  }

  #pragma unroll
  for(int mf=0;mf<2;mf++){
    float inv[4];
    #pragma unroll
    for(int r=0;r<4;r++) inv[r] = 1.f/lrow[mf][r];
    #pragma unroll
    for(int nf=0;nf<8;nf++){
      #pragma unroll
      for(int r=0;r<4;r++){
        size_t row = (size_t)qb*128 + w*32 + mf*16 + lk*4 + r;
        size_t col = (size_t)h*128 + nf*16 + lr;
        O[row*3072 + col] = usbf(o[mf][nf][r]*inv[r]);
      }
    }
  }
}

// ---------------- MFMA GEMM, bf16 A, fp32 W[K][N], 2-phase double-buffered ----
// C[M,N] = epilogue(A[M,K] @ W[K][N] + bias)
// mode 0: bf16 out (+bias)   mode 1: gelu(v+bias) -> bf16
// mode 3: atomicAdd(C_f32, (gate?gate[col]:1) * acc)   [bias via k_initC]
__global__ __launch_bounds__(256,4) void k_gemmW(
    const unsigned short* __restrict__ A, long lda,
    const float* __restrict__ W, long ldw,
    const float* __restrict__ bias,
    void* __restrict__ Cp, long ldc,
    int K, int KS, int mode,
    const float* __restrict__ gate)
{
  __shared__ unsigned short Als[2][128*32];   // 2 x 8 KB
  __shared__ unsigned short Bls[2][128*40];   // 2 x 10 KB padded bf16 B^T
  const int t = threadIdx.x;
  const int bn = blockIdx.x, bm = blockIdx.y;
  const int zs = blockIdx.z;
  const int Kc = K / KS, kbeg = zs*Kc, kend = kbeg + Kc;

  const unsigned short* Ab = A + (size_t)bm*128*lda;
  const float* Wb = W + (size_t)bn*128;

  const int lane = t & 63, wid = t>>6, wr = wid>>1, wc = wid&1;
  const int lr = lane & 15, lk = lane>>4;
  const int srow = (lane>>2);
  const int soff = (lane&3)*8;
  const int wcb = (t&31)*4;        // W stage: col base (4 floats)
  const int wrb = (t>>5)*4;        // W stage: row base (4 k rows)

  f32x4 acc[4][4];
  #pragma unroll
  for(int i=0;i<4;i++)
    #pragma unroll
    for(int j=0;j<4;j++) acc[i][j] = {0.f,0.f,0.f,0.f};

  float4 wreg[4];

  // ---- prologue: stage tile kbeg into buf 0 ----
  gload16(Ab + (size_t)(     wid*16 + srow)*lda + kbeg + soff, &Als[0][(     wid*16)*32]);
  gload16(Ab + (size_t)(64 + wid*16 + srow)*lda + kbeg + soff, &Als[0][(64 + wid*16)*32]);
  #pragma unroll
  for(int j=0;j<4;j++)
    wreg[j] = *(const float4*)(Wb + (size_t)(kbeg + wrb + j)*ldw + wcb);
  #pragma unroll
  for(int i=0;i<4;i++){
    u16x4 pk = { usbf(wreg[0][i]), usbf(wreg[1][i]), usbf(wreg[2][i]), usbf(wreg[3][i]) };
    *(u16x4*)&Bls[0][(wcb+i)*40 + wrb] = pk;
  }
  __syncthreads();

  unsigned short* AlsC = &Als[0][0]; unsigned short* AlsN = &Als[1][0];
  unsigned short* BlsC = &Bls[0][0]; unsigned short* BlsN = &Bls[1][0];

  for(int k0=kbeg; k0<kend; k0+=32){
    const bool has = (k0 + 32 < kend);
    if(has){
      int kn = k0 + 32;
      gload16(Ab + (size_t)(     wid*16 + srow)*lda + kn + soff, AlsN + (     wid*16)*32);
      gload16(Ab + (size_t)(64 + wid*16 + srow)*lda + kn + soff, AlsN + (64 + wid*16)*32);
      #pragma unroll
      for(int j=0;j<4;j++)
        wreg[j] = *(const float4*)(Wb + (size_t)(kn + wrb + j)*ldw + wcb);
    }
    // compute current tile
    {
      bf16x8 af[4], bfr[4];
      #pragma unroll
      for(int mf=0;mf<4;mf++) af[mf]  = *(const bf16x8*)&AlsC[(wr*64 + mf*16 + lr)*32 + lk*8];
      #pragma unroll
      for(int nf=0;nf<4;nf++) bfr[nf] = *(const bf16x8*)&BlsC[(wc*64 + nf*16 + lr)*40 + lk*8];
      #pragma unroll
      for(int mf=0;mf<4;mf++)
        #pragma unroll
        for(int nf=0;nf<4;nf++)
          acc[mf][nf] = __builtin_amdgcn_mfma_f32_16x16x32_bf16(af[mf], bfr[nf], acc[mf][nf], 0,0,0);
    }
    if(has){
      #pragma unroll
      for(int i=0;i<4;i++){
        u16x4 pk = { usbf(wreg[0][i]), usbf(wreg[1][i]), usbf(wreg[2][i]), usbf(wreg[3][i]) };
        *(u16x4*)&BlsN[(wcb+i)*40 + wrb] = pk;
      }
    }
    __syncthreads();
    unsigned short* tmp;
    tmp = AlsC; AlsC = AlsN; AlsN = tmp;
    tmp = BlsC; BlsC = BlsN; BlsN = tmp;
  }

  unsigned short* C16 = (unsigned short*)Cp;
  float* C32 = (float*)Cp;
  #pragma unroll
  for(int mf=0;mf<4;mf++){
    #pragma unroll
    for(int nf=0;nf<4;nf++){
      #pragma unroll
      for(int r=0;r<4;r++){
        size_t row = (size_t)bm*128 + wr*64 + mf*16 + lk*4 + r;
        size_t col = (size_t)bn*128 + wc*64 + nf*16 + lr;
        float v = acc[mf][nf][r];
        if(mode==0){
          C16[row*ldc + col] = f2bf(v + (bias ? bias[col] : 0.f));
        } else if(mode==1){
          C16[row*ldc + col] = f2bf(gelu_tanh(v + (bias ? bias[col] : 0.f)));
        } else {
          float g = gate ? gate[col] : 1.f;
          atomicAdd(&C32[row*ldc + col], g*v);
        }
      }
    }
  }
}

// ---------------- launch ----------------

extern "C" void kernel_launch(void* const* d_in, const int* in_sizes, int n_in,
                              void* d_out, int out_size, void* d_ws, size_t ws_size,
                              hipStream_t stream){
  const float* hidden_states = (const float*)d_in[0];
  const float* enc_states    = (const float*)d_in[1];
  const float* temb          = (const float*)d_in[3];
  const float* rope_cos      = (const float*)d_in[4];
  const float* rope_sin      = (const float*)d_in[5];
  const float* w_img_mod     = (const float*)d_in[6];
  const float* b_img_mod     = (const float*)d_in[7];
  const float* w_txt_mod     = (const float*)d_in[8];
  const float* b_txt_mod     = (const float*)d_in[9];
  const float* norm_q_w      = (const float*)d_in[10];
  const float* norm_k_w      = (const float*)d_in[11];
  const float* norm_aq_w     = (const float*)d_in[12];
  const float* norm_ak_w     = (const float*)d_in[13];
  const float* w_qkv   = (const float*)d_in[14];
  const float* b_qkv   = (const float*)d_in[15];
  const float* w_aqkv  = (const float*)d_in[16];
  const float* b_aqkv  = (const float*)d_in[17];
  const float* w_out_  = (const float*)d_in[18];
  const float* b_out_  = (const float*)d_in[19];
  const float* w_aout  = (const float*)d_in[20];
  const float* b_aout  = (const float*)d_in[21];
  const float* w_mlp1i = (const float*)d_in[22];
  const float* b_mlp1i = (const float*)d_in[23];
  const float* w_mlp2i = (const float*)d_in[24];
  const float* b_mlp2i = (const float*)d_in[25];
  const float* w_mlp1t = (const float*)d_in[26];
  const float* b_mlp1t = (const float*)d_in[27];
  const float* w_mlp2t = (const float*)d_in[28];
  const float* b_mlp2t = (const float*)d_in[29];

  char* ws = (char*)d_ws;
  float* mod    = (float*)(ws + 0);                        // 2*6*3072 f32
  float* silu_t = (float*)(ws + 147456);
  unsigned short* imgm = (unsigned short*)(ws + 159744);   // 1024x3072 bf16
  unsigned short* txtm = (unsigned short*)(ws + 6451200);  // 512x3072 bf16
  float* hid = (float*)(ws + 9596928);                     // 1024x3072 f32
  float* enc = (float*)(ws + 22179840);                    // 512x3072 f32
  unsigned short* Qb  = (unsigned short*)(ws + 47345664);  // 1536x3072 bf16
  unsigned short* Kb  = (unsigned short*)(ws + 56782848);
  unsigned short* Vb  = (unsigned short*)(ws + 66220032);  // dead after vtrans
  unsigned short* attnb = (unsigned short*)(ws + 66220032);// 1536x3072 bf16 (reuses Vb)
  unsigned short* VTb = (unsigned short*)(ws + 75657216);  // 24x128x1536 bf16
  unsigned short* qkvi = (unsigned short*)(ws + 141717504);// 1024x9216 bf16
  unsigned short* qkvt = (unsigned short*)(ws + 160591872);// 512x9216 bf16
  unsigned short* mlph = (unsigned short*)(ws + 103968768);// 1024x12288 bf16

  float* out_enc = (float*)d_out;
  float* out_hid = (float*)d_out + (size_t)STX*DIMX;

  // modulation params
  k_silu<<<12,256,0,stream>>>(temb, silu_t);
  k_modinit<<<144,256,0,stream>>>(b_img_mod, b_txt_mod, mod);
  k_modgemv<<<288,256,0,stream>>>(w_img_mod, w_txt_mod, silu_t, mod);

  // LN + modulate (mod1)
  k_lnmod<<<SIX,256,0,stream>>>(hidden_states, mod + 0,     imgm);
  k_lnmod<<<STX,256,0,stream>>>(enc_states,    mod + 18432, txtm);

  // QKV projections (weights consumed fp32 directly)
  k_gemmW<<<dim3(72,8,1),256,0,stream>>>(imgm,3072, w_qkv,9216, b_qkv,
      qkvi,9216, 3072,1, 0, nullptr);
  k_gemmW<<<dim3(72,4,1),256,0,stream>>>(txtm,3072, w_aqkv,9216, b_aqkv,
      qkvt,9216, 3072,1, 0, nullptr);

  // RMS + RoPE -> Q,K,V [1536][24][128]; V transpose
  k_rmsrope<<<dim3(1536,24),64,0,stream>>>(qkvt, qkvi, norm_q_w, norm_k_w,
      norm_aq_w, norm_ak_w, rope_cos, rope_sin, Qb, Kb, Vb);
  k_vtrans<<<dim3(24,24),256,0,stream>>>(Vb, VTb);

  // fused flash attention -> attnb bf16
  k_fattn<<<dim3(12,24),256,0,stream>>>(Qb, Kb, VTb, attnb);

  // output projections, fused residual+gate1, split-K atomics
  k_initC<<<512*3,256,0,stream>>>(enc, enc_states, mod + 18432 + 2*3072, b_aout);
  k_initC<<<1024*3,256,0,stream>>>(hid, hidden_states, mod + 2*3072, b_out_);
  k_gemmW<<<dim3(24,4,8),256,0,stream>>>(attnb,3072, w_aout,3072, nullptr,
      enc,3072, 3072,8, 3, mod + 18432 + 2*3072);
  k_gemmW<<<dim3(24,8,4),256,0,stream>>>(attnb + (size_t)512*3072,3072, w_out_,3072, nullptr,
      hid,3072, 3072,4, 3, mod + 2*3072);

  // img MLP
  k_lnmod<<<SIX,256,0,stream>>>(hid, mod + 3*3072, imgm);
  k_gemmW<<<dim3(96,8,1),256,0,stream>>>(imgm,3072, w_mlp1i,12288, b_mlp1i,
      mlph,12288, 3072,1, 1, nullptr);
  k_initC<<<1024*3,256,0,stream>>>(out_hid, hid, mod + 5*3072, b_mlp2i);
  k_gemmW<<<dim3(24,8,4),256,0,stream>>>(mlph,12288, w_mlp2i,3072, nullptr,
      out_hid,3072, 12288,4, 3, mod + 5*3072);

  // txt MLP
  k_lnmod<<<STX,256,0,stream>>>(enc, mod + 18432 + 3*3072, txtm);
  k_gemmW<<<dim3(96,4,1),256,0,stream>>>(txtm,3072, w_mlp1t,12288, b_mlp1t,
      mlph,12288, 3072,1, 1, nullptr);
  k_initC<<<512*3,256,0,stream>>>(out_enc, enc, mod + 18432 + 5*3072, b_mlp2t);
  k_gemmW<<<dim3(24,4,8),256,0,stream>>>(mlph,12288, w_mlp2t,3072, nullptr,
      out_enc,3072, 12288,8, 3, mod + 18432 + 5*3072);
}

// Round 8
// 1103.199 us; speedup vs baseline: 1.2436x; 1.0832x over previous
//
#include <hip/hip_runtime.h>

#define DIMX 3072
#define STX 512
#define SIX 1024
#define SQX 1536
#define FFX 12288

typedef __attribute__((ext_vector_type(4))) float f32x4;
typedef __attribute__((ext_vector_type(8))) __bf16 bf16x8;
typedef __attribute__((ext_vector_type(4))) int i32x4;
typedef __attribute__((ext_vector_type(4))) unsigned short u16x4;

__device__ __forceinline__ unsigned short f2bf(float f){
  unsigned u = __builtin_bit_cast(unsigned, f);
  u += 0x7FFFu + ((u>>16)&1u);
  return (unsigned short)(u>>16);
}
__device__ __forceinline__ unsigned short usbf(float x){
  return __builtin_bit_cast(unsigned short, (__bf16)x);
}
__device__ __forceinline__ float bf2f(unsigned short h){
  unsigned u = ((unsigned)h)<<16;
  return __builtin_bit_cast(float, u);
}
__device__ __forceinline__ float gelu_tanh(float x){
  float x3 = x*x*x;
  float z = 0.7978845608028654f*(x + 0.044715f*x3);
  z = fminf(fmaxf(z, -15.f), 15.f);
  float e = exp2f(z*2.8853900817779268f);   // e^(2z)
  float th = (e-1.f)/(e+1.f);
  return 0.5f*x*(1.f+th);
}

// async global->LDS, 16B per lane; lds base must be wave-uniform
__device__ __forceinline__ void gload16(const void* g, void* l){
  __builtin_amdgcn_global_load_lds(
      (const __attribute__((address_space(1))) void*)g,
      (__attribute__((address_space(3))) void*)l,
      16, 0, 0);
}

// ---------------- small kernels ----------------

__global__ void k_silu(const float* __restrict__ temb, float* __restrict__ out){
  int i = blockIdx.x*256 + threadIdx.x;
  if(i < DIMX){
    float x = temb[i];
    out[i] = x / (1.f + exp2f(-x*1.4426950408889634f));
  }
}

__global__ void k_modinit(const float* __restrict__ b_img, const float* __restrict__ b_txt,
                          float* __restrict__ mod){
  int idx = blockIdx.x*256 + threadIdx.x;   // 0..36863
  int mat = idx / 18432; int r = idx % 18432;
  int i = r/6, j = r%6;
  const float* b = mat ? b_txt : b_img;
  mod[mat*18432 + j*3072 + i] = b[r];
}

__global__ void k_modgemv(const float* __restrict__ w_img, const float* __restrict__ w_txt,
                          const float* __restrict__ silu_t, float* __restrict__ mod){
  int bz = blockIdx.x;
  int ks = bz & 7; bz >>= 3;
  int nc = bz % 18; int mat = bz / 18;
  const float* W = mat ? w_txt : w_img;
  __shared__ float st[384];
  int k0 = ks*384;
  for(int i = threadIdx.x; i < 384; i += 256) st[i] = silu_t[k0+i];
  __syncthreads();
  int n0 = nc*1024 + threadIdx.x*4;
  float ax=0.f, ay=0.f, az=0.f, aw=0.f;
  const float* Wp = W + (size_t)k0*18432 + n0;
  #pragma unroll 4
  for(int k=0;k<384;k++){
    float4 w = *(const float4*)(Wp + (size_t)k*18432);
    float s = st[k];
    ax += s*w.x; ay += s*w.y; az += s*w.z; aw += s*w.w;
  }
  float* md = mod + mat*18432;
  float vals[4] = {ax, ay, az, aw};
  #pragma unroll
  for(int j=0;j<4;j++){
    int n = n0+j; int i = n/6, jj = n%6;
    atomicAdd(&md[jj*3072 + i], vals[j]);
  }
}

// merged init: rows [0,R0) -> set0, rows [R0,R0+R1) -> set1
// out = res + gate*bias per 3072-wide row
__global__ void k_initC2(float* __restrict__ out0, const float* __restrict__ res0,
                         const float* __restrict__ gate0, const float* __restrict__ bias0,
                         float* __restrict__ out1, const float* __restrict__ res1,
                         const float* __restrict__ gate1, const float* __restrict__ bias1,
                         int R0){
  long i = ((long)blockIdx.x*256 + threadIdx.x)*4;
  int row = (int)(i / 3072);
  int col = (int)(i % 3072);
  const float* res; const float* gate; const float* bias; float* out;
  long off;
  if(row < R0){ res=res0; gate=gate0; bias=bias0; out=out0; off=i; }
  else        { res=res1; gate=gate1; bias=bias1; out=out1; off=i - (long)R0*3072; }
  float4 r = *(const float4*)(res + off);
  float4 g = *(const float4*)(gate + col);
  float4 b = *(const float4*)(bias + col);
  float4 o = {r.x + g.x*b.x, r.y + g.y*b.y, r.z + g.z*b.z, r.w + g.w*b.w};
  *(float4*)(out + off) = o;
}

// merged LayerNorm+modulate: block < R0 -> set0 else set1
__global__ void k_lnmod2(const float* __restrict__ x0, const float* __restrict__ modp0,
                         unsigned short* __restrict__ out0,
                         const float* __restrict__ x1, const float* __restrict__ modp1,
                         unsigned short* __restrict__ out1, int R0){
  int row = blockIdx.x, t = threadIdx.x;
  const float* x; const float* modp; unsigned short* out;
  if(row < R0){ x=x0; modp=modp0; out=out0; }
  else        { x=x1; modp=modp1; out=out1; row -= R0; }
  const float* xr = x + (size_t)row*DIMX;
  float4 v0 = *(const float4*)(xr + t*4);
  float4 v1 = *(const float4*)(xr + 1024 + t*4);
  float4 v2 = *(const float4*)(xr + 2048 + t*4);
  float s  = v0.x+v0.y+v0.z+v0.w + v1.x+v1.y+v1.z+v1.w + v2.x+v2.y+v2.z+v2.w;
  float s2 = v0.x*v0.x+v0.y*v0.y+v0.z*v0.z+v0.w*v0.w
           + v1.x*v1.x+v1.y*v1.y+v1.z*v1.z+v1.w*v1.w
           + v2.x*v2.x+v2.y*v2.y+v2.z*v2.z+v2.w*v2.w;
  #pragma unroll
  for(int o=32;o>0;o>>=1){ s += __shfl_xor(s,o); s2 += __shfl_xor(s2,o); }
  __shared__ float rs_[4], rs2_[4];
  int wid = t>>6;
  if((t&63)==0){ rs_[wid]=s; rs2_[wid]=s2; }
  __syncthreads();
  float S  = rs_[0]+rs_[1]+rs_[2]+rs_[3];
  float S2 = rs2_[0]+rs2_[1]+rs2_[2]+rs2_[3];
  float mu = S*(1.f/3072.f);
  float var = S2*(1.f/3072.f) - mu*mu;
  float rstd = rsqrtf(var + 1e-6f);
  #pragma unroll
  for(int j=0;j<3;j++){
    int c = j*1024 + t*4;
    float4 sh = *(const float4*)(modp + c);
    float4 sc = *(const float4*)(modp + 3072 + c);
    float4 xv = (j==0)?v0:((j==1)?v1:v2);
    unsigned short h0 = f2bf((xv.x-mu)*rstd*(sc.x+1.f)+sh.x);
    unsigned short h1 = f2bf((xv.y-mu)*rstd*(sc.y+1.f)+sh.y);
    unsigned short h2 = f2bf((xv.z-mu)*rstd*(sc.z+1.f)+sh.z);
    unsigned short h3 = f2bf((xv.w-mu)*rstd*(sc.w+1.f)+sh.w);
    unsigned long long pk = (unsigned long long)(h0 | ((unsigned)h1<<16))
                          | ((unsigned long long)(h2 | ((unsigned)h3<<16))<<32);
    *(unsigned long long*)(out + (size_t)row*DIMX + c) = pk;
  }
}

// RMSNorm(q,k) + RoPE, V passthrough. grid (1536, 24), block 64.
__global__ void k_rmsrope(const unsigned short* __restrict__ qkv_txt,
                          const unsigned short* __restrict__ qkv_img,
                          const float* __restrict__ nqw, const float* __restrict__ nkw,
                          const float* __restrict__ naqw, const float* __restrict__ nakw,
                          const float* __restrict__ cosb, const float* __restrict__ sinb,
                          unsigned short* __restrict__ Q, unsigned short* __restrict__ K,
                          unsigned short* __restrict__ V){
  int s = blockIdx.x, h = blockIdx.y, t = threadIdx.x;
  bool txt = s < STX;
  const unsigned short* src = txt ? (qkv_txt + (size_t)s*9216)
                                  : (qkv_img + (size_t)(s-STX)*9216);
  const float* qw = txt ? naqw : nqw;
  const float* kw = txt ? nakw : nkw;
  int d0 = 2*t;
  float q1 = bf2f(src[h*128 + d0]),        q2 = bf2f(src[h*128 + d0 + 1]);
  float k1 = bf2f(src[3072 + h*128 + d0]), k2 = bf2f(src[3072 + h*128 + d0 + 1]);
  float v1 = bf2f(src[6144 + h*128 + d0]), v2 = bf2f(src[6144 + h*128 + d0 + 1]);
  float sq = q1*q1 + q2*q2, sk = k1*k1 + k2*k2;
  #pragma unroll
  for(int o=32;o>0;o>>=1){ sq += __shfl_xor(sq,o); sk += __shfl_xor(sk,o); }
  float rq = rsqrtf(sq*(1.f/128.f) + 1e-6f);
  float rk = rsqrtf(sk*(1.f/128.f) + 1e-6f);
  q1 *= rq*qw[d0]; q2 *= rq*qw[d0+1];
  k1 *= rk*kw[d0]; k2 *= rk*kw[d0+1];
  float c1 = cosb[(size_t)s*128 + d0], c2 = cosb[(size_t)s*128 + d0 + 1];
  float s1 = sinb[(size_t)s*128 + d0], s2 = sinb[(size_t)s*128 + d0 + 1];
  float Q1 = q1*c1 - q2*s1, Q2 = q2*c2 + q1*s2;
  float K1 = k1*c1 - k2*s1, K2 = k2*c2 + k1*s2;
  size_t o = ((size_t)s*24 + h)*128 + d0;
  Q[o] = f2bf(Q1); Q[o+1] = f2bf(Q2);
  K[o] = f2bf(K1); K[o+1] = f2bf(K2);
  V[o] = f2bf(v1); V[o+1] = f2bf(v2);
}

// V[s][h][d] -> VT[h][d][s]. grid (24 s-tiles, 24 heads), block 256.
__global__ void k_vtrans(const unsigned short* __restrict__ V, unsigned short* __restrict__ VT){
  __shared__ unsigned short tile[64][136];
  int st = blockIdx.x, h = blockIdx.y, t = threadIdx.x;
  int s0 = st*64;
  {
    int s = t>>2;
    #pragma unroll
    for(int i=0;i<4;i++){
      int oct = ((t&3)<<2) + i;     // 0..15
      i32x4 d = *(const i32x4*)(V + ((size_t)(s0+s)*24 + h)*128 + oct*8);
      *(i32x4*)&tile[s][oct*8] = d;
    }
  }
  __syncthreads();
  {
    int d0 = t>>3; int strip = t&7;
    #pragma unroll
    for(int i=0;i<4;i++){
      int d = d0 + i*32;
      unsigned short h8[8];
      #pragma unroll
      for(int j=0;j<8;j++) h8[j] = tile[strip*8 + j][d];
      unsigned a0 = h8[0] | ((unsigned)h8[1]<<16);
      unsigned a1 = h8[2] | ((unsigned)h8[3]<<16);
      unsigned a2 = h8[4] | ((unsigned)h8[5]<<16);
      unsigned a3 = h8[6] | ((unsigned)h8[7]<<16);
      i32x4 dv = {(int)a0,(int)a1,(int)a2,(int)a3};
      *(i32x4*)(VT + ((size_t)h*128 + d)*1536 + s0 + strip*8) = dv;
    }
  }
}

// ---------------- fused flash attention ----------------
// grid (12 q-blocks, 24 heads), 256 threads (4 waves); each wave owns 32 q rows.
// K/V staged with source pre-swizzle (chunk ^= row&3), reads XOR back.
__global__ __launch_bounds__(256,2) void k_fattn(
    const unsigned short* __restrict__ Q,
    const unsigned short* __restrict__ Kb,
    const unsigned short* __restrict__ VT,
    unsigned short* __restrict__ O)
{
  __shared__ unsigned short Kls[4][64][32];
  __shared__ unsigned short Vls[2][128][32];
  __shared__ unsigned short Pls[128][72];
  const int t = threadIdx.x;
  const int qb = blockIdx.x, h = blockIdx.y;
  const int lane = t&63, w = t>>6;
  const int lr = lane&15, lk = lane>>4;
  const float SC  = 0.08838834764831845f;
  const float L2E = 1.4426950408889634f;
  const int schunk = ((lane&3) ^ ((lane>>2)&3))*8;   // pre-swizzled source chunk
  const int rswz   = ((lr&3)<<3);                    // read-side XOR (shorts)

  bf16x8 qf[2][4];
  {
    const unsigned short* qp = Q + ((size_t)(qb*128 + w*32 + lr)*3072) + h*128 + lk*8;
    #pragma unroll
    for(int mf=0;mf<2;mf++)
      #pragma unroll
      for(int ks=0;ks<4;ks++)
        qf[mf][ks] = *(const bf16x8*)(qp + (size_t)mf*16*3072 + ks*32);
  }

  f32x4 o[2][8];
  #pragma unroll
  for(int i=0;i<2;i++)
    #pragma unroll
    for(int j=0;j<8;j++) o[i][j] = (f32x4){0.f,0.f,0.f,0.f};
  float mrow[2][4], lrow[2][4];
  #pragma unroll
  for(int i=0;i<2;i++)
    #pragma unroll
    for(int r=0;r<4;r++){ mrow[i][r] = -3.0e30f; lrow[i][r] = 0.f; }

  for(int kv0=0; kv0<SQX; kv0+=64){
    __syncthreads();
    {
      const unsigned short* kp = Kb + ((size_t)(kv0 + (lane>>2))*3072) + h*128 + w*32 + schunk;
      #pragma unroll
      for(int i=0;i<4;i++)
        gload16(kp + (size_t)i*16*3072, &Kls[w][i*16][0]);
    }
    {
      int c = w>>1;
      const unsigned short* vp = VT + ((size_t)(h*128 + (w&1)*64 + (lane>>2)))*1536 + kv0 + c*32 + schunk;
      #pragma unroll
      for(int j=0;j<4;j++)
        gload16(vp + (size_t)j*16*1536, &Vls[c][(w&1)*64 + j*16][0]);
    }
    __syncthreads();

    f32x4 s[2][4];
    #pragma unroll
    for(int mf=0;mf<2;mf++)
      #pragma unroll
      for(int nf=0;nf<4;nf++) s[mf][nf] = (f32x4){0.f,0.f,0.f,0.f};
    #pragma unroll
    for(int ks=0;ks<4;ks++){
      bf16x8 kf[4];
      #pragma unroll
      for(int nf=0;nf<4;nf++) kf[nf] = *(const bf16x8*)&Kls[ks][nf*16+lr][(lk*8) ^ rswz];
      #pragma unroll
      for(int mf=0;mf<2;mf++)
        #pragma unroll
        for(int nf=0;nf<4;nf++)
          s[mf][nf] = __builtin_amdgcn_mfma_f32_16x16x32_bf16(qf[mf][ks], kf[nf], s[mf][nf], 0,0,0);
    }

    #pragma unroll
    for(int mf=0;mf<2;mf++){
      #pragma unroll
      for(int r=0;r<4;r++){
        float v = fmaxf(fmaxf(s[mf][0][r], s[mf][1][r]), fmaxf(s[mf][2][r], s[mf][3][r]));
        #pragma unroll
        for(int d=1; d<16; d<<=1) v = fmaxf(v, __shfl_xor(v, d));
        float nm = fmaxf(mrow[mf][r], v*SC);
        float fac = exp2f((mrow[mf][r]-nm)*L2E);
        mrow[mf][r] = nm;
        float rs = 0.f;
        #pragma unroll
        for(int nf=0;nf<4;nf++){
          float p = exp2f((s[mf][nf][r]*SC - nm)*L2E);
          s[mf][nf][r] = p;
          rs += p;
        }
        #pragma unroll
        for(int d=1; d<16; d<<=1) rs += __shfl_xor(rs, d);
        lrow[mf][r] = lrow[mf][r]*fac + rs;
        #pragma unroll
        for(int nf=0;nf<8;nf++) o[mf][nf][r] *= fac;
      }
    }

    #pragma unroll
    for(int mf=0;mf<2;mf++)
      #pragma unroll
      for(int nf=0;nf<4;nf++)
        #pragma unroll
        for(int r=0;r<4;r++)
          Pls[w*32 + mf*16 + lk*4 + r][nf*16 + lr] = usbf(s[mf][nf][r]);

    #pragma unroll
    for(int ks2=0; ks2<2; ks2++){
      bf16x8 pa[2];
      #pragma unroll
      for(int mf=0;mf<2;mf++)
        pa[mf] = *(const bf16x8*)&Pls[w*32 + mf*16 + lr][ks2*32 + lk*8];
      #pragma unroll
      for(int nf=0;nf<8;nf++){
        bf16x8 vf = *(const bf16x8*)&Vls[ks2][nf*16+lr][(lk*8) ^ rswz];
        #pragma unroll
        for(int mf=0;mf<2;mf++)
          o[mf][nf] = __builtin_amdgcn_mfma_f32_16x16x32_bf16(pa[mf], vf, o[mf][nf], 0,0,0);
      }
    }
  }

  #pragma unroll
  for(int mf=0;mf<2;mf++){
    float inv[4];
    #pragma unroll
    for(int r=0;r<4;r++) inv[r] = 1.f/lrow[mf][r];
    #pragma unroll
    for(int nf=0;nf<8;nf++){
      #pragma unroll
      for(int r=0;r<4;r++){
        size_t row = (size_t)qb*128 + w*32 + mf*16 + lk*4 + r;
        size_t col = (size_t)h*128 + nf*16 + lr;
        O[row*3072 + col] = usbf(o[mf][nf][r]*inv[r]);
      }
    }
  }
}

// ---------------- merged MFMA GEMM, bf16 A, fp32 W[K][N], 2-phase dbuf -------
// Two independent problem sets share one launch: bm-tiles [0,nM0) -> set0,
// [nM0, nM0+nM1) -> set1. C[M,N] = epilogue(A@W + bias).
// mode 0: bf16 out (+bias)  mode 1: gelu -> bf16  mode 3: atomicAdd f32 gate*acc
__global__ __launch_bounds__(256,4) void k_gemmW(
    const unsigned short* __restrict__ A0, const unsigned short* __restrict__ A1, long lda,
    const float* __restrict__ W0, const float* __restrict__ W1, long ldw,
    const float* __restrict__ bias0, const float* __restrict__ bias1,
    void* __restrict__ C0, void* __restrict__ C1, long ldc,
    int nM0, int K, int KS, int mode,
    const float* __restrict__ gate0, const float* __restrict__ gate1)
{
  __shared__ unsigned short Als[2][128*32];   // 2 x 8 KB, source-swizzled granules
  __shared__ unsigned short Bls[2][128*40];   // 2 x 10 KB, padded + XOR-swizzled
  const int t = threadIdx.x;
  const int bn = blockIdx.x;
  int bm = blockIdx.y;
  const bool sel1 = (bm >= nM0);
  const unsigned short* A = sel1 ? A1 : A0;
  const float* W  = sel1 ? W1 : W0;
  const float* bias = sel1 ? bias1 : bias0;
  const float* gate = sel1 ? gate1 : gate0;
  void* Cp = sel1 ? C1 : C0;
  if(sel1) bm -= nM0;
  const int zs = blockIdx.z;
  const int Kc = K / KS, kbeg = zs*Kc, kend = kbeg + Kc;

  const unsigned short* Ab = A + (size_t)bm*128*lda;
  const float* Wb = W + (size_t)bn*128;

  const int lane = t & 63, wid = t>>6, wr = wid>>1, wc = wid&1;
  const int lr = lane & 15, lk = lane>>4;
  const int srow = (lane>>2);
  const int soff = (((lane&3) ^ ((lane>>2)&3))*8);   // pre-swizzled A source chunk
  const int aswz = (lk*8) ^ ((lr&3)<<3);             // A read offset (shorts)
  const int bswz = (lk*8) ^ (((lr>>2)&3)<<3);        // B read offset (shorts)
  const int u = t&31, v = t>>5;
  const int wcol = (v*4) ^ ((u&3)<<3);               // B write col (shorts)

  f32x4 acc[4][4];
  #pragma unroll
  for(int i=0;i<4;i++)
    #pragma unroll
    for(int j=0;j<4;j++) acc[i][j] = {0.f,0.f,0.f,0.f};

  float4 wreg[4];

  // prologue: stage tile kbeg into buf 0
  gload16(Ab + (size_t)(     wid*16 + srow)*lda + kbeg + soff, &Als[0][(     wid*16)*32]);
  gload16(Ab + (size_t)(64 + wid*16 + srow)*lda + kbeg + soff, &Als[0][(64 + wid*16)*32]);
  #pragma unroll
  for(int j=0;j<4;j++)
    wreg[j] = *(const float4*)(Wb + (size_t)(kbeg + v*4 + j)*ldw + u*4);
  #pragma unroll
  for(int i=0;i<4;i++){
    u16x4 pk = { usbf(wreg[0][i]), usbf(wreg[1][i]), usbf(wreg[2][i]), usbf(wreg[3][i]) };
    *(u16x4*)&Bls[0][(u*4+i)*40 + wcol] = pk;
  }
  __syncthreads();

  unsigned short* AlsC = &Als[0][0]; unsigned short* AlsN = &Als[1][0];
  unsigned short* BlsC = &Bls[0][0]; unsigned short* BlsN = &Bls[1][0];

  for(int k0=kbeg; k0<kend; k0+=32){
    const bool has = (k0 + 32 < kend);
    if(has){
      int kn = k0 + 32;
      gload16(Ab + (size_t)(     wid*16 + srow)*lda + kn + soff, AlsN + (     wid*16)*32);
      gload16(Ab + (size_t)(64 + wid*16 + srow)*lda + kn + soff, AlsN + (64 + wid*16)*32);
      #pragma unroll
      for(int j=0;j<4;j++)
        wreg[j] = *(const float4*)(Wb + (size_t)(kn + v*4 + j)*ldw + u*4);
    }
    {
      bf16x8 af[4], bfr[4];
      #pragma unroll
      for(int mf=0;mf<4;mf++) af[mf]  = *(const bf16x8*)&AlsC[(wr*64 + mf*16 + lr)*32 + aswz];
      #pragma unroll
      for(int nf=0;nf<4;nf++) bfr[nf] = *(const bf16x8*)&BlsC[(wc*64 + nf*16 + lr)*40 + bswz];
      #pragma unroll
      for(int mf=0;mf<4;mf++)
        #pragma unroll
        for(int nf=0;nf<4;nf++)
          acc[mf][nf] = __builtin_amdgcn_mfma_f32_16x16x32_bf16(af[mf], bfr[nf], acc[mf][nf], 0,0,0);
    }
    if(has){
      #pragma unroll
      for(int i=0;i<4;i++){
        u16x4 pk = { usbf(wreg[0][i]), usbf(wreg[1][i]), usbf(wreg[2][i]), usbf(wreg[3][i]) };
        *(u16x4*)&BlsN[(u*4+i)*40 + wcol] = pk;
      }
    }
    __syncthreads();
    unsigned short* tmp;
    tmp = AlsC; AlsC = AlsN; AlsN = tmp;
    tmp = BlsC; BlsC = BlsN; BlsN = tmp;
  }

  unsigned short* C16 = (unsigned short*)Cp;
  float* C32 = (float*)Cp;
  #pragma unroll
  for(int mf=0;mf<4;mf++){
    #pragma unroll
    for(int nf=0;nf<4;nf++){
      #pragma unroll
      for(int r=0;r<4;r++){
        size_t row = (size_t)bm*128 + wr*64 + mf*16 + lk*4 + r;
        size_t col = (size_t)bn*128 + wc*64 + nf*16 + lr;
        float v2 = acc[mf][nf][r];
        if(mode==0){
          C16[row*ldc + col] = f2bf(v2 + (bias ? bias[col] : 0.f));
        } else if(mode==1){
          C16[row*ldc + col] = f2bf(gelu_tanh(v2 + (bias ? bias[col] : 0.f)));
        } else {
          float g = gate ? gate[col] : 1.f;
          atomicAdd(&C32[row*ldc + col], g*v2);
        }
      }
    }
  }
}

// ---------------- launch ----------------

extern "C" void kernel_launch(void* const* d_in, const int* in_sizes, int n_in,
                              void* d_out, int out_size, void* d_ws, size_t ws_size,
                              hipStream_t stream){
  const float* hidden_states = (const float*)d_in[0];
  const float* enc_states    = (const float*)d_in[1];
  const float* temb          = (const float*)d_in[3];
  const float* rope_cos      = (const float*)d_in[4];
  const float* rope_sin      = (const float*)d_in[5];
  const float* w_img_mod     = (const float*)d_in[6];
  const float* b_img_mod     = (const float*)d_in[7];
  const float* w_txt_mod     = (const float*)d_in[8];
  const float* b_txt_mod     = (const float*)d_in[9];
  const float* norm_q_w      = (const float*)d_in[10];
  const float* norm_k_w      = (const float*)d_in[11];
  const float* norm_aq_w     = (const float*)d_in[12];
  const float* norm_ak_w     = (const float*)d_in[13];
  const float* w_qkv   = (const float*)d_in[14];
  const float* b_qkv   = (const float*)d_in[15];
  const float* w_aqkv  = (const float*)d_in[16];
  const float* b_aqkv  = (const float*)d_in[17];
  const float* w_out_  = (const float*)d_in[18];
  const float* b_out_  = (const float*)d_in[19];
  const float* w_aout  = (const float*)d_in[20];
  const float* b_aout  = (const float*)d_in[21];
  const float* w_mlp1i = (const float*)d_in[22];
  const float* b_mlp1i = (const float*)d_in[23];
  const float* w_mlp2i = (const float*)d_in[24];
  const float* b_mlp2i = (const float*)d_in[25];
  const float* w_mlp1t = (const float*)d_in[26];
  const float* b_mlp1t = (const float*)d_in[27];
  const float* w_mlp2t = (const float*)d_in[28];
  const float* b_mlp2t = (const float*)d_in[29];

  char* ws = (char*)d_ws;
  float* mod    = (float*)(ws + 0);                        // 2*6*3072 f32
  float* silu_t = (float*)(ws + 147456);
  unsigned short* imgm = (unsigned short*)(ws + 159744);   // 1024x3072 bf16
  unsigned short* txtm = (unsigned short*)(ws + 6451200);  // 512x3072 bf16
  float* hid = (float*)(ws + 9596928);                     // 1024x3072 f32
  float* enc = (float*)(ws + 22179840);                    // 512x3072 f32
  unsigned short* Qb  = (unsigned short*)(ws + 47345664);  // 1536x3072 bf16
  unsigned short* Kb  = (unsigned short*)(ws + 56782848);
  unsigned short* Vb  = (unsigned short*)(ws + 66220032);  // dead after vtrans
  unsigned short* attnb = (unsigned short*)(ws + 66220032);// 1536x3072 bf16 (reuses Vb)
  unsigned short* VTb = (unsigned short*)(ws + 75657216);  // 24x128x1536 bf16
  unsigned short* mlphI = (unsigned short*)(ws + 103968768);// 1024x12288 bf16
  unsigned short* mlphT = (unsigned short*)(ws + 129134592);// 512x12288 bf16 (ends 141717504)
  unsigned short* qkvi = (unsigned short*)(ws + 141717504);// 1024x9216 bf16
  unsigned short* qkvt = (unsigned short*)(ws + 160591872);// 512x9216 bf16

  float* out_enc = (float*)d_out;
  float* out_hid = (float*)d_out + (size_t)STX*DIMX;

  // modulation params
  k_silu<<<12,256,0,stream>>>(temb, silu_t);
  k_modinit<<<144,256,0,stream>>>(b_img_mod, b_txt_mod, mod);
  k_modgemv<<<288,256,0,stream>>>(w_img_mod, w_txt_mod, silu_t, mod);

  // LN + modulate (mod1), img+txt merged
  k_lnmod2<<<SQX,256,0,stream>>>(hidden_states, mod + 0, imgm,
                                 enc_states, mod + 18432, txtm, SIX);

  // QKV projections, img+txt merged (fp32 weights consumed directly)
  k_gemmW<<<dim3(72,12,1),256,0,stream>>>(imgm, txtm, 3072,
      w_qkv, w_aqkv, 9216, b_qkv, b_aqkv,
      qkvi, qkvt, 9216, 8, 3072,1, 0, nullptr,nullptr);

  // RMS + RoPE -> Q,K,V [1536][24][128]; V transpose
  k_rmsrope<<<dim3(1536,24),64,0,stream>>>(qkvt, qkvi, norm_q_w, norm_k_w,
      norm_aq_w, norm_ak_w, rope_cos, rope_sin, Qb, Kb, Vb);
  k_vtrans<<<dim3(24,24),256,0,stream>>>(Vb, VTb);

  // fused flash attention -> attnb bf16
  k_fattn<<<dim3(12,24),256,0,stream>>>(Qb, Kb, VTb, attnb);

  // residual+gate1 inits, then merged out-projections (split-K atomics)
  k_initC2<<<4608,256,0,stream>>>(hid, hidden_states, mod + 2*3072, b_out_,
                                  enc, enc_states, mod + 18432 + 2*3072, b_aout, SIX);
  k_gemmW<<<dim3(24,12,4),256,0,stream>>>(attnb + (size_t)512*3072, attnb, 3072,
      w_out_, w_aout, 3072, nullptr, nullptr,
      hid, enc, 3072, 8, 3072,4, 3, mod + 2*3072, mod + 18432 + 2*3072);

  // LN + modulate (mod2), merged
  k_lnmod2<<<SQX,256,0,stream>>>(hid, mod + 3*3072, imgm,
                                 enc, mod + 18432 + 3*3072, txtm, SIX);

  // MLP1 merged (gelu epilogue)
  k_gemmW<<<dim3(96,12,1),256,0,stream>>>(imgm, txtm, 3072,
      w_mlp1i, w_mlp1t, 12288, b_mlp1i, b_mlp1t,
      mlphI, mlphT, 12288, 8, 3072,1, 1, nullptr,nullptr);

  // output inits, then MLP2 merged (split-K atomics into d_out)
  k_initC2<<<4608,256,0,stream>>>(out_hid, hid, mod + 5*3072, b_mlp2i,
                                  out_enc, enc, mod + 18432 + 5*3072, b_mlp2t, SIX);
  k_gemmW<<<dim3(24,12,4),256,0,stream>>>(mlphI, mlphT, 12288,
      w_mlp2i, w_mlp2t, 3072, nullptr, nullptr,
      out_hid, out_enc, 3072, 8, 12288,4, 3, mod + 5*3072, mod + 18432 + 5*3072);
}